// Round 1
// baseline (485.642 us; speedup 1.0000x reference)
//
#include <hip/hip_runtime.h>
#include <cstdint>
#include <cstddef>

// ---------------------------------------------------------------------------
// MLA forward (B=2, S=2048, DIM=2048, H=16, Q_RANK=KV_RANK=512,
//              D_NOPE=128, D_ROPE=64, D_V=128, D_QK=192)
//
// Pipeline:
//  1. cvt x + 5 weights f32->bf16 (once per launch, into ws)
//  2. q_lat = x @ wq_a^T        (bf16 MFMA GEMM, f32 out)
//  3. q_latn = rmsnorm(q_lat)   -> bf16
//  4. kv_a = x @ wkv_a^T        (f32 out)
//  5. k_pe = rope(kv_a[:,512:]) -> bf16 ; kv_latn = rmsnorm(kv_a[:,:512]) -> bf16
//  6. q_full = q_latn @ wq_b^T  (f32) ; rope+pack -> q_bf [bh][s][192]
//  7. kv_b = kv_latn @ wkv_b^T  (f32) ; pack k_bf [bh][s][192], v^T [bh][dv][s]
//  8. flash attention (swapped-QK^T online softmax) -> attn bf16 [b][s][h*128+dv]
//  9. out = attn @ wo^T (f32 -> d_out)
//
// Assumptions (flagged for diagnosis if round fails):
//  - d_out is float* (reference output dtype f32)
//  - ws_size >= ~181 MB (early-return guard otherwise -> output stays poisoned)
//  - mfma_f32_16x16x32_bf16: A row=l&15,k=8*(l>>4)+i ; B col=l&15 same k;
//    C col=l&15,row=4*(l>>4)+reg ; operands short8 (per verified guide)
// ---------------------------------------------------------------------------

typedef unsigned short u16;
typedef unsigned int u32;
typedef __attribute__((ext_vector_type(8))) short bf16x8;
typedef __attribute__((ext_vector_type(4))) float floatx4;

#define MFMA16x16x32 __builtin_amdgcn_mfma_f32_16x16x32_bf16

__device__ __forceinline__ u16 f2bf(float f) {
  u32 u = __float_as_uint(f);
  u32 r = (u + 0x7fffu + ((u >> 16) & 1u)) >> 16;
  return (u16)r;
}

// ---------------- f32 -> bf16 convert (vectorized, grid-stride) -------------
__global__ __launch_bounds__(256) void cvt_bf16(const float* __restrict__ in,
                                                u16* __restrict__ out, int n4) {
  int i = blockIdx.x * 256 + threadIdx.x;
  int stride = gridDim.x * 256;
  for (; i < n4; i += stride) {
    float4 v = ((const float4*)in)[i];
    ushort4 o;
    o.x = f2bf(v.x); o.y = f2bf(v.y); o.z = f2bf(v.z); o.w = f2bf(v.w);
    ((ushort4*)out)[i] = o;
  }
}

// ---------------- GEMM: C(M,N) f32 = A(M,K) bf16 @ B(N,K)^T bf16 ------------
// 256 threads = 4 waves (2x2), tile 128 x BN, BK=32, 16x16x32 MFMA.
// All launches use N % BN == 0, M % 128 == 0, K % 32 == 0 (true for every call).
template <int BN>
__global__ __launch_bounds__(256) void gemm_bt(const u16* __restrict__ A,
                                               const u16* __restrict__ B,
                                               float* __restrict__ C,
                                               int M, int N, int K) {
  constexpr int FN = BN / 32;
  __shared__ alignas(16) u16 As[128][40];  // 40-stride: 2-way-max bank aliasing
  __shared__ alignas(16) u16 Bs[BN][40];
  const int m0 = blockIdx.y * 128, n0 = blockIdx.x * BN;
  const int t = threadIdx.x;
  const int wv = t >> 6, lane = t & 63, g = lane >> 4, qq = lane & 15;
  const int wr = wv >> 1, wc = wv & 1;
  const floatx4 fz = {0.f, 0.f, 0.f, 0.f};
  floatx4 acc[4][FN];
  for (int m = 0; m < 4; ++m)
    for (int n = 0; n < FN; ++n) acc[m][n] = fz;

  for (int k0 = 0; k0 < K; k0 += 32) {
    __syncthreads();
#pragma unroll
    for (int i = 0; i < 2; ++i) {  // A tile: 128x32 = 512 segs of 8 bf16
      int s8 = t + i * 256;
      int row = s8 >> 2, c8 = s8 & 3;
      *(int4*)&As[row][c8 * 8] =
          *(const int4*)&A[(size_t)(m0 + row) * K + k0 + c8 * 8];
    }
#pragma unroll
    for (int i = 0; i < BN / 64; ++i) {  // B tile: BN x 32
      int s8 = t + i * 256;
      int row = s8 >> 2, c8 = s8 & 3;
      *(int4*)&Bs[row][c8 * 8] =
          *(const int4*)&B[(size_t)(n0 + row) * K + k0 + c8 * 8];
    }
    __syncthreads();
    bf16x8 af[4], bfr[FN];
#pragma unroll
    for (int m = 0; m < 4; ++m)
      af[m] = *(const bf16x8*)&As[wr * 64 + m * 16 + qq][g * 8];
#pragma unroll
    for (int n = 0; n < FN; ++n)
      bfr[n] = *(const bf16x8*)&Bs[wc * (BN / 2) + n * 16 + qq][g * 8];
#pragma unroll
    for (int m = 0; m < 4; ++m)
#pragma unroll
      for (int n = 0; n < FN; ++n)
        acc[m][n] = MFMA16x16x32(af[m], bfr[n], acc[m][n], 0, 0, 0);
  }
#pragma unroll
  for (int m = 0; m < 4; ++m)
    for (int n = 0; n < FN; ++n)
      for (int r = 0; r < 4; ++r) {
        int row = m0 + wr * 64 + m * 16 + 4 * g + r;
        int col = n0 + wc * (BN / 2) + n * 16 + qq;
        C[(size_t)row * N + col] = acc[m][n][r];
      }
}

// ---------------- RMSNorm over 512 cols, f32 in -> bf16 out -----------------
__global__ __launch_bounds__(256) void rmsnorm_bf16(const float* __restrict__ in,
                                                    int stride,
                                                    const float* __restrict__ w,
                                                    u16* __restrict__ out) {
  const int row = blockIdx.x, t = threadIdx.x;
  __shared__ float wsum[4];
  float2 v = *(const float2*)&in[(size_t)row * stride + 2 * t];
  float ss = v.x * v.x + v.y * v.y;
#pragma unroll
  for (int off = 1; off < 64; off <<= 1) ss += __shfl_xor(ss, off);
  if ((t & 63) == 0) wsum[t >> 6] = ss;
  __syncthreads();
  float tot = wsum[0] + wsum[1] + wsum[2] + wsum[3];
  float r = rsqrtf(tot * (1.f / 512.f) + 1e-6f);
  out[(size_t)row * 512 + 2 * t] = f2bf(v.x * r * w[2 * t]);
  out[(size_t)row * 512 + 2 * t + 1] = f2bf(v.y * r * w[2 * t + 1]);
}

// ---------------- RoPE on k_pe (kv_a cols 512..575) -> bf16 -----------------
__global__ __launch_bounds__(256) void rope_kpe(const float* __restrict__ kva,
                                                const float* __restrict__ fc,
                                                u16* __restrict__ kpe) {
  int idx = blockIdx.x * 256 + threadIdx.x;  // 4096*32
  int row = idx >> 5, j = idx & 31;
  int s = row & 2047;
  float xr = kva[(size_t)row * 576 + 512 + 2 * j];
  float xi = kva[(size_t)row * 576 + 512 + 2 * j + 1];
  float c = fc[(s * 32 + j) * 2], sn = fc[(s * 32 + j) * 2 + 1];
  u32 lo = f2bf(xr * c - xi * sn), hi = f2bf(xr * sn + xi * c);
  *(u32*)&kpe[(size_t)row * 64 + 2 * j] = lo | (hi << 16);
}

// ---------------- RoPE + pack q: (b,s,h,192) f32 -> [bh][s][192] bf16 -------
__global__ __launch_bounds__(256) void rope_pack_q(const float* __restrict__ qf,
                                                   const float* __restrict__ fc,
                                                   u16* __restrict__ qbf) {
  int idx = blockIdx.x * 256 + threadIdx.x;  // 4096*16*96
  int j = idx % 96;
  int rh = idx / 96;
  int h = rh & 15, row = rh >> 4;
  int b = row >> 11, s = row & 2047;
  const float* src = qf + (size_t)row * 3072 + h * 192;
  u16* dst = qbf + ((size_t)(b * 16 + h) * 2048 + s) * 192;
  if (j < 64) {
    u32 lo = f2bf(src[2 * j]), hi = f2bf(src[2 * j + 1]);
    *(u32*)&dst[2 * j] = lo | (hi << 16);
  } else {
    int jp = j - 64;
    float xr = src[128 + 2 * jp], xi = src[128 + 2 * jp + 1];
    float c = fc[(s * 32 + jp) * 2], sn = fc[(s * 32 + jp) * 2 + 1];
    u32 lo = f2bf(xr * c - xi * sn), hi = f2bf(xr * sn + xi * c);
    *(u32*)&dst[128 + 2 * jp] = lo | (hi << 16);
  }
}

// ---------------- pack k: kv_b nope + broadcast k_pe -> [bh][s][192] --------
__global__ __launch_bounds__(256) void pack_k(const float* __restrict__ kvb,
                                              const u16* __restrict__ kpe,
                                              u16* __restrict__ kbf) {
  int idx = blockIdx.x * 256 + threadIdx.x;  // 4096*16*96
  int j = idx % 96;
  int rh = idx / 96;
  int h = rh & 15, row = rh >> 4;
  int b = row >> 11, s = row & 2047;
  u16* dst = kbf + ((size_t)(b * 16 + h) * 2048 + s) * 192;
  if (j < 64) {
    const float* src = kvb + (size_t)row * 4096 + h * 256;
    u32 lo = f2bf(src[2 * j]), hi = f2bf(src[2 * j + 1]);
    *(u32*)&dst[2 * j] = lo | (hi << 16);
  } else {
    int jp = j - 64;
    *(u32*)&dst[128 + 2 * jp] = *(const u32*)&kpe[(size_t)row * 64 + 2 * jp];
  }
}

// ---------------- transpose v: kv_b[...,128:256] -> vt [bh][dv=128][s] ------
__global__ __launch_bounds__(256) void transpose_v(const float* __restrict__ kvb,
                                                   u16* __restrict__ vt) {
  __shared__ u16 T[32][34];
  const int bh = blockIdx.z, b = bh >> 4, h = bh & 15;
  const int s0 = blockIdx.x * 32, d0 = blockIdx.y * 32;
  const int tx = threadIdx.x & 31, ty = threadIdx.x >> 5;
#pragma unroll
  for (int i = 0; i < 4; ++i) {
    int sl = ty + i * 8;
    float v = kvb[(size_t)(b * 2048 + s0 + sl) * 4096 + h * 256 + 128 + d0 + tx];
    T[sl][tx] = f2bf(v);
  }
  __syncthreads();
#pragma unroll
  for (int i = 0; i < 4; ++i) {
    int dl = ty + i * 8;
    vt[((size_t)bh * 128 + d0 + dl) * 2048 + s0 + tx] = T[tx][dl];
  }
}

// ---------------- flash attention -------------------------------------------
// grid (qt=32, bh=32), 256 thr = 4 waves; wave handles 16 q-rows, 32 keys/iter.
// S^T = mfma(K_frag, Q_frag): softmax state per lane (q = lane&15).
// P -> per-wave LDS -> A-frag; PV with V^T tiles (16x16x32).
#define SCALE_F 0.07216878364870323f  // 192^-0.5
__global__ __launch_bounds__(256) void flash_attn(const u16* __restrict__ Q,
                                                  const u16* __restrict__ Kc,
                                                  const u16* __restrict__ VT,
                                                  u16* __restrict__ O) {
  __shared__ alignas(16) u16 Ks[32][200];   // 32 keys x 192 (pad 200)
  __shared__ alignas(16) u16 Vs[128][40];   // 128 dv x 32 keys (pad 40)
  __shared__ alignas(16) u16 Ps[4][16][40]; // per-wave P transpose buffer
  const int qt = blockIdx.x, bh = blockIdx.y;
  const int t = threadIdx.x, wv = t >> 6, lane = t & 63;
  const int g = lane >> 4, qq = lane & 15;
  const int qrow0 = qt * 64 + wv * 16;

  bf16x8 qf[6];
  {
    const u16* qp = Q + ((size_t)bh * 2048 + qrow0 + qq) * 192;
#pragma unroll
    for (int kk = 0; kk < 6; ++kk) qf[kk] = *(const bf16x8*)&qp[kk * 32 + g * 8];
  }
  const floatx4 fz = {0.f, 0.f, 0.f, 0.f};
  floatx4 oacc[8];
#pragma unroll
  for (int i = 0; i < 8; ++i) oacc[i] = fz;
  float m_run = -1e30f, l_run = 0.f;
  const int q_glob = qrow0 + qq;
  const int my_last = qrow0 + 15;
  const int nkt = qt * 2 + 2;

  for (int kt = 0; kt < nkt; ++kt) {
    const int k0 = kt * 32;
    __syncthreads();
#pragma unroll
    for (int i = 0; i < 3; ++i) {  // K tile: 32x192 = 768 segs
      int s8 = t + i * 256;
      int kr = s8 / 24, c8 = s8 - kr * 24;
      *(int4*)&Ks[kr][c8 * 8] =
          *(const int4*)&Kc[((size_t)bh * 2048 + k0 + kr) * 192 + c8 * 8];
    }
#pragma unroll
    for (int i = 0; i < 2; ++i) {  // V^T tile: 128x32 = 512 segs
      int s8 = t + i * 256;
      int vr = s8 >> 2, c8 = s8 & 3;
      *(int4*)&Vs[vr][c8 * 8] =
          *(const int4*)&VT[((size_t)bh * 128 + vr) * 2048 + k0 + c8 * 8];
    }
    __syncthreads();
    if (k0 > my_last) continue;  // wave-uniform; barriers stay aligned

    floatx4 st0 = fz, st1 = fz;
#pragma unroll
    for (int kk = 0; kk < 6; ++kk) {
      bf16x8 a0 = *(const bf16x8*)&Ks[qq][kk * 32 + g * 8];
      bf16x8 a1 = *(const bf16x8*)&Ks[16 + qq][kk * 32 + g * 8];
      st0 = MFMA16x16x32(a0, qf[kk], st0, 0, 0, 0);
      st1 = MFMA16x16x32(a1, qf[kk], st1, 0, 0, 0);
    }
    float p[8];
    float mx = -1e30f;
#pragma unroll
    for (int r = 0; r < 4; ++r) {
      int key0 = k0 + 4 * g + r, key1 = key0 + 16;
      float v0 = st0[r] * SCALE_F, v1 = st1[r] * SCALE_F;
      if (key0 > q_glob) v0 = -1e30f;
      if (key1 > q_glob) v1 = -1e30f;
      p[r] = v0;
      p[4 + r] = v1;
      mx = fmaxf(mx, fmaxf(v0, v1));
    }
    mx = fmaxf(mx, __shfl_xor(mx, 16));
    mx = fmaxf(mx, __shfl_xor(mx, 32));
    float m_new = fmaxf(m_run, mx);
    float sum = 0.f;
#pragma unroll
    for (int i = 0; i < 8; ++i) {
      p[i] = __expf(p[i] - m_new);
      sum += p[i];
    }
    sum += __shfl_xor(sum, 16);
    sum += __shfl_xor(sum, 32);
    float alpha = __expf(m_run - m_new);
    l_run = l_run * alpha + sum;
    m_run = m_new;
#pragma unroll
    for (int r = 0; r < 4; ++r) {
      Ps[wv][qq][4 * g + r] = f2bf(p[r]);
      Ps[wv][qq][16 + 4 * g + r] = f2bf(p[4 + r]);
    }
    bf16x8 pf = *(const bf16x8*)&Ps[wv][qq][g * 8];
    float a4[4];
#pragma unroll
    for (int r = 0; r < 4; ++r) a4[r] = __shfl(alpha, 4 * g + r);
#pragma unroll
    for (int t8 = 0; t8 < 8; ++t8) {
#pragma unroll
      for (int r = 0; r < 4; ++r) oacc[t8][r] *= a4[r];
      bf16x8 vf = *(const bf16x8*)&Vs[t8 * 16 + qq][g * 8];
      oacc[t8] = MFMA16x16x32(pf, vf, oacc[t8], 0, 0, 0);
    }
  }
  float li[4];
#pragma unroll
  for (int r = 0; r < 4; ++r) li[r] = 1.f / __shfl(l_run, 4 * g + r);
  const int b = bh >> 4, h = bh & 15;
#pragma unroll
  for (int t8 = 0; t8 < 8; ++t8)
    for (int r = 0; r < 4; ++r) {
      size_t row = (size_t)b * 2048 + qrow0 + 4 * g + r;
      O[row * 2048 + h * 128 + t8 * 16 + qq] = f2bf(oacc[t8][r] * li[r]);
    }
}

// ---------------------------------------------------------------------------
extern "C" void kernel_launch(void* const* d_in, const int* in_sizes, int n_in,
                              void* d_out, int out_size, void* d_ws,
                              size_t ws_size, hipStream_t stream) {
  (void)in_sizes; (void)n_in; (void)out_size;
  const float* x = (const float*)d_in[0];
  const float* fc = (const float*)d_in[1];
  const float* wqa = (const float*)d_in[2];
  const float* wqb = (const float*)d_in[3];
  const float* qnw = (const float*)d_in[4];
  const float* wkva = (const float*)d_in[5];
  const float* kvnw = (const float*)d_in[6];
  const float* wkvb = (const float*)d_in[7];
  const float* wo = (const float*)d_in[8];
  float* out = (float*)d_out;
  char* ws = (char*)d_ws;

  size_t off = 0;
  auto alloc = [&](size_t bytes) {
    size_t o = off;
    off += (bytes + 255) & ~(size_t)255;
    return o;
  };
  const size_t o_xbf = alloc(16777216);   // x bf16; later aliased by attn_out
  const size_t o_wqa = alloc(2097152);
  const size_t o_wqb = alloc(3145728);
  const size_t o_wkva = alloc(2359296);
  const size_t o_wkvb = alloc(4194304);
  const size_t o_wo = alloc(8388608);
  const size_t o_qln = alloc(4194304);    // q_lat normed bf16
  const size_t o_kvln = alloc(4194304);   // kv_lat normed bf16
  const size_t o_kpe = alloc(524288);     // roped k_pe bf16
  const size_t o_big = alloc(67108864);   // f32 scratch: qlat/kva -> qfull -> kvb
  const size_t o_qbf = alloc(25165824);   // q packed [bh][s][192]
  const size_t o_kbf = alloc(25165824);   // k packed [bh][s][192]
  const size_t o_vt = alloc(16777216);    // v^T [bh][128][2048]
  if (ws_size < off) return;  // insufficient workspace -> visible failure

  u16* xbf = (u16*)(ws + o_xbf);
  u16* wqab = (u16*)(ws + o_wqa);
  u16* wqbb = (u16*)(ws + o_wqb);
  u16* wkvab = (u16*)(ws + o_wkva);
  u16* wkvbb = (u16*)(ws + o_wkvb);
  u16* wob = (u16*)(ws + o_wo);
  u16* qlatn = (u16*)(ws + o_qln);
  u16* kvlatn = (u16*)(ws + o_kvln);
  u16* kpe = (u16*)(ws + o_kpe);
  float* qlat = (float*)(ws + o_big);               // 4096x512 f32
  float* kva = (float*)(ws + o_big + 8388608);      // 4096x576 f32
  float* qfull = (float*)(ws + o_big);              // 4096x3072 f32 (after kva dead)
  float* kvb = (float*)(ws + o_big);                // 4096x4096 f32 (after qfull dead)
  u16* qbf = (u16*)(ws + o_qbf);
  u16* kbf = (u16*)(ws + o_kbf);
  u16* vt = (u16*)(ws + o_vt);
  u16* attnbf = (u16*)(ws + o_xbf);  // aliases xbf (dead after kv_a GEMM)

  auto cvt = [&](const float* src, u16* dst, int n) {
    int n4 = n / 4;
    int nb = (n4 + 255) / 256;
    if (nb > 2048) nb = 2048;
    cvt_bf16<<<nb, 256, 0, stream>>>(src, dst, n4);
  };
  cvt(x, xbf, 8388608);
  cvt(wqa, wqab, 1048576);
  cvt(wkva, wkvab, 1179648);
  cvt(wqb, wqbb, 1572864);
  cvt(wkvb, wkvbb, 2097152);
  cvt(wo, wob, 4194304);

  // q_lat = x @ wq_a^T ; kv_a = x @ wkv_a^T
  gemm_bt<64><<<dim3(8, 32), 256, 0, stream>>>(xbf, wqab, qlat, 4096, 512, 2048);
  rmsnorm_bf16<<<4096, 256, 0, stream>>>(qlat, 512, qnw, qlatn);
  gemm_bt<64><<<dim3(9, 32), 256, 0, stream>>>(xbf, wkvab, kva, 4096, 576, 2048);
  rope_kpe<<<512, 256, 0, stream>>>(kva, fc, kpe);
  rmsnorm_bf16<<<4096, 256, 0, stream>>>(kva, 576, kvnw, kvlatn);

  // q = rmsnorm(q_lat) @ wq_b^T -> rope+pack
  gemm_bt<128><<<dim3(24, 32), 256, 0, stream>>>(qlatn, wqbb, qfull, 4096, 3072, 512);
  rope_pack_q<<<24576, 256, 0, stream>>>(qfull, fc, qbf);

  // kv = rmsnorm(kv_lat) @ wkv_b^T -> pack k, transpose v
  gemm_bt<128><<<dim3(32, 32), 256, 0, stream>>>(kvlatn, wkvbb, kvb, 4096, 4096, 512);
  pack_k<<<24576, 256, 0, stream>>>(kvb, kpe, kbf);
  transpose_v<<<dim3(64, 4, 32), 256, 0, stream>>>(kvb, vt);

  // attention + output projection
  flash_attn<<<dim3(32, 32), 256, 0, stream>>>(qbf, kbf, vt, attnbf);
  gemm_bt<128><<<dim3(16, 32), 256, 0, stream>>>(attnbf, wob, out, 4096, 2048, 2048);
}

// Round 2
// 371.450 us; speedup vs baseline: 1.3074x; 1.3074x over previous
//
#include <hip/hip_runtime.h>
#include <cstdint>
#include <cstddef>

// ---------------------------------------------------------------------------
// MLA forward (B=2, S=2048, DIM=2048, H=16, Q_RANK=KV_RANK=512,
//              D_NOPE=128, D_ROPE=64, D_V=128, D_QK=192)
// Round 2: flash v2 (QBLK=128/KV=64, gload_lds + XOR swizzle, defer-max,
//          longest-first dispatch) + m97-style GEMM (gload_lds staging).
// ---------------------------------------------------------------------------

typedef unsigned short u16;
typedef unsigned int u32;
typedef unsigned long long u64;
typedef __attribute__((ext_vector_type(8))) short bf16x8;
typedef __attribute__((ext_vector_type(4))) float floatx4;

#define MFMA16x16x32 __builtin_amdgcn_mfma_f32_16x16x32_bf16

__device__ __forceinline__ u16 f2bf(float f) {
  u32 u = __float_as_uint(f);
  u32 r = (u + 0x7fffu + ((u >> 16) & 1u)) >> 16;
  return (u16)r;
}

__device__ __forceinline__ void gload16(const void* g, void* l) {
  __builtin_amdgcn_global_load_lds(
      (const __attribute__((address_space(1))) void*)g,
      (__attribute__((address_space(3))) void*)l, 16, 0, 0);
}

// ---------------- f32 -> bf16 convert (vectorized, grid-stride) -------------
__global__ __launch_bounds__(256) void cvt_bf16(const float* __restrict__ in,
                                                u16* __restrict__ out, int n4) {
  int i = blockIdx.x * 256 + threadIdx.x;
  int stride = gridDim.x * 256;
  for (; i < n4; i += stride) {
    float4 v = ((const float4*)in)[i];
    ushort4 o;
    o.x = f2bf(v.x); o.y = f2bf(v.y); o.z = f2bf(v.z); o.w = f2bf(v.w);
    ((ushort4*)out)[i] = o;
  }
}

// ---------------- GEMM: C(M,N) f32 = A(M,K) bf16 @ B(N,K)^T bf16 ------------
// m97-structure: 128xBN tile, BK=32, 4 waves (2x2), global_load_lds staging
// with slot-XOR swizzle (pre-swizzled source + swizzled ds_read; 2-way free).
template <int BN>
__global__ __launch_bounds__(256) void gemm_bt(const u16* __restrict__ A,
                                               const u16* __restrict__ B,
                                               float* __restrict__ C,
                                               int M, int N, int K) {
  constexpr int FN = BN / 32;
  __shared__ alignas(16) u16 As[128 * 32];
  __shared__ alignas(16) u16 Bs[BN * 32];
  const int m0 = blockIdx.y * 128, n0 = blockIdx.x * BN;
  const int t = threadIdx.x;
  const int wv = t >> 6, lane = t & 63, g = lane >> 4, qq = lane & 15;
  const int wr = wv >> 1, wc = wv & 1;
  const int fsw = (qq >> 1) & 3;  // read-side XOR (row>>1)&3 == (qq>>1)&3
  const floatx4 fz = {0.f, 0.f, 0.f, 0.f};
  floatx4 acc[4][FN];
#pragma unroll
  for (int m = 0; m < 4; ++m)
#pragma unroll
    for (int n = 0; n < FN; ++n) acc[m][n] = fz;

  for (int k0 = 0; k0 < K; k0 += 32) {
    __syncthreads();
#pragma unroll
    for (int i = 0; i < 2; ++i) {  // A tile: 128 rows x 4 slots of 16B
      int seg = t + i * 256;
      int row = seg >> 2, sl = seg & 3;
      int gsl = sl ^ ((row >> 1) & 3);
      gload16(&A[(size_t)(m0 + row) * K + k0 + gsl * 8],
              &As[(size_t)(wv * 64 + i * 256) * 8]);
    }
#pragma unroll
    for (int i = 0; i < BN / 64; ++i) {  // B tile: BN rows x 4 slots
      int seg = t + i * 256;
      int row = seg >> 2, sl = seg & 3;
      int gsl = sl ^ ((row >> 1) & 3);
      gload16(&B[(size_t)(n0 + row) * K + k0 + gsl * 8],
              &Bs[(size_t)(wv * 64 + i * 256) * 8]);
    }
    __syncthreads();
    bf16x8 af[4], bfr[FN];
#pragma unroll
    for (int m = 0; m < 4; ++m)
      af[m] = *(const bf16x8*)&As[(wr * 64 + m * 16 + qq) * 32 + ((g ^ fsw) * 8)];
#pragma unroll
    for (int n = 0; n < FN; ++n)
      bfr[n] = *(const bf16x8*)&Bs[(wc * (BN / 2) + n * 16 + qq) * 32 + ((g ^ fsw) * 8)];
#pragma unroll
    for (int m = 0; m < 4; ++m)
#pragma unroll
      for (int n = 0; n < FN; ++n)
        acc[m][n] = MFMA16x16x32(af[m], bfr[n], acc[m][n], 0, 0, 0);
  }
#pragma unroll
  for (int m = 0; m < 4; ++m)
#pragma unroll
    for (int n = 0; n < FN; ++n)
#pragma unroll
      for (int r = 0; r < 4; ++r) {
        int row = m0 + wr * 64 + m * 16 + 4 * g + r;
        int col = n0 + wc * (BN / 2) + n * 16 + qq;
        C[(size_t)row * N + col] = acc[m][n][r];
      }
}

// ---------------- RMSNorm over 512 cols, f32 in -> bf16 out -----------------
__global__ __launch_bounds__(256) void rmsnorm_bf16(const float* __restrict__ in,
                                                    int stride,
                                                    const float* __restrict__ w,
                                                    u16* __restrict__ out) {
  const int row = blockIdx.x, t = threadIdx.x;
  __shared__ float wsum[4];
  float2 v = *(const float2*)&in[(size_t)row * stride + 2 * t];
  float ss = v.x * v.x + v.y * v.y;
#pragma unroll
  for (int off = 1; off < 64; off <<= 1) ss += __shfl_xor(ss, off);
  if ((t & 63) == 0) wsum[t >> 6] = ss;
  __syncthreads();
  float tot = wsum[0] + wsum[1] + wsum[2] + wsum[3];
  float r = rsqrtf(tot * (1.f / 512.f) + 1e-6f);
  out[(size_t)row * 512 + 2 * t] = f2bf(v.x * r * w[2 * t]);
  out[(size_t)row * 512 + 2 * t + 1] = f2bf(v.y * r * w[2 * t + 1]);
}

// ---------------- RoPE on k_pe (kv_a cols 512..575) -> bf16 -----------------
__global__ __launch_bounds__(256) void rope_kpe(const float* __restrict__ kva,
                                                const float* __restrict__ fc,
                                                u16* __restrict__ kpe) {
  int idx = blockIdx.x * 256 + threadIdx.x;  // 4096*32
  int row = idx >> 5, j = idx & 31;
  int s = row & 2047;
  float xr = kva[(size_t)row * 576 + 512 + 2 * j];
  float xi = kva[(size_t)row * 576 + 512 + 2 * j + 1];
  float c = fc[(s * 32 + j) * 2], sn = fc[(s * 32 + j) * 2 + 1];
  u32 lo = f2bf(xr * c - xi * sn), hi = f2bf(xr * sn + xi * c);
  *(u32*)&kpe[(size_t)row * 64 + 2 * j] = lo | (hi << 16);
}

// ---------------- RoPE + pack q: (b,s,h,192) f32 -> [bh][s][192] bf16 -------
__global__ __launch_bounds__(256) void rope_pack_q(const float* __restrict__ qf,
                                                   const float* __restrict__ fc,
                                                   u16* __restrict__ qbf) {
  int idx = blockIdx.x * 256 + threadIdx.x;  // 4096*16*96
  int j = idx % 96;
  int rh = idx / 96;
  int h = rh & 15, row = rh >> 4;
  int b = row >> 11, s = row & 2047;
  const float* src = qf + (size_t)row * 3072 + h * 192;
  u16* dst = qbf + ((size_t)(b * 16 + h) * 2048 + s) * 192;
  if (j < 64) {
    u32 lo = f2bf(src[2 * j]), hi = f2bf(src[2 * j + 1]);
    *(u32*)&dst[2 * j] = lo | (hi << 16);
  } else {
    int jp = j - 64;
    float xr = src[128 + 2 * jp], xi = src[128 + 2 * jp + 1];
    float c = fc[(s * 32 + jp) * 2], sn = fc[(s * 32 + jp) * 2 + 1];
    u32 lo = f2bf(xr * c - xi * sn), hi = f2bf(xr * sn + xi * c);
    *(u32*)&dst[128 + 2 * jp] = lo | (hi << 16);
  }
}

// ---------------- pack k: kv_b nope + broadcast k_pe -> [bh][s][192] --------
__global__ __launch_bounds__(256) void pack_k(const float* __restrict__ kvb,
                                              const u16* __restrict__ kpe,
                                              u16* __restrict__ kbf) {
  int idx = blockIdx.x * 256 + threadIdx.x;  // 4096*16*96
  int j = idx % 96;
  int rh = idx / 96;
  int h = rh & 15, row = rh >> 4;
  int b = row >> 11, s = row & 2047;
  u16* dst = kbf + ((size_t)(b * 16 + h) * 2048 + s) * 192;
  if (j < 64) {
    const float* src = kvb + (size_t)row * 4096 + h * 256;
    u32 lo = f2bf(src[2 * j]), hi = f2bf(src[2 * j + 1]);
    *(u32*)&dst[2 * j] = lo | (hi << 16);
  } else {
    int jp = j - 64;
    *(u32*)&dst[128 + 2 * jp] = *(const u32*)&kpe[(size_t)row * 64 + 2 * jp];
  }
}

// ---------------- transpose v: kv_b[...,128:256] -> vt [bh][dv=128][s] ------
__global__ __launch_bounds__(256) void transpose_v(const float* __restrict__ kvb,
                                                   u16* __restrict__ vt) {
  __shared__ u16 T[32][34];
  const int bh = blockIdx.z, b = bh >> 4, h = bh & 15;
  const int s0 = blockIdx.x * 32, d0 = blockIdx.y * 32;
  const int tx = threadIdx.x & 31, ty = threadIdx.x >> 5;
#pragma unroll
  for (int i = 0; i < 4; ++i) {
    int sl = ty + i * 8;
    float v = kvb[(size_t)(b * 2048 + s0 + sl) * 4096 + h * 256 + 128 + d0 + tx];
    T[sl][tx] = f2bf(v);
  }
  __syncthreads();
#pragma unroll
  for (int i = 0; i < 4; ++i) {
    int dl = ty + i * 8;
    vt[((size_t)bh * 128 + d0 + dl) * 2048 + s0 + tx] = T[tx][dl];
  }
}

// ---------------- flash attention v2 ----------------------------------------
// grid 512 = (qt 16 x bh 32), longest-first; 4 waves x 32 q-rows (2 qgrps),
// KV=64/step staged via gload_lds (XOR-swizzled), 2x 32-key substeps,
// swapped QK^T online softmax with defer-max (THR=8).
#define SCALE_F 0.07216878364870323f  // 192^-0.5
__global__ __launch_bounds__(256) void flash_attn(const u16* __restrict__ Q,
                                                  const u16* __restrict__ Kc,
                                                  const u16* __restrict__ VT,
                                                  u16* __restrict__ O) {
  __shared__ alignas(16) u16 Ks[64 * 192];   // row*192 + slot'*8 (24 slots/row)
  __shared__ alignas(16) u16 Vs[128 * 64];   // row*64 + slot'*8 (8 slots/row)
  __shared__ alignas(16) u16 Ps[4][16][72];  // per-wave P transpose (pad 72)
  const int bid = blockIdx.x;
  const int qt = 15 - (bid >> 5);  // longest blocks dispatched first
  const int bh = bid & 31;
  const int t = threadIdx.x, wv = t >> 6, lane = t & 63;
  const int g = lane >> 4, qq = lane & 15;
  const int qrow0 = qt * 128 + wv * 32;
  const int my_last = qrow0 + 31;

  bf16x8 qf[2][6];
#pragma unroll
  for (int qg = 0; qg < 2; ++qg)
#pragma unroll
    for (int kk = 0; kk < 6; ++kk)
      qf[qg][kk] = *(const bf16x8*)
          &Q[((size_t)bh * 2048 + qrow0 + qg * 16 + qq) * 192 + kk * 32 + g * 8];

  const floatx4 fz = {0.f, 0.f, 0.f, 0.f};
  floatx4 oacc[2][8];
#pragma unroll
  for (int qg = 0; qg < 2; ++qg)
#pragma unroll
    for (int d = 0; d < 8; ++d) oacc[qg][d] = fz;
  float m_run[2] = {-1e30f, -1e30f}, l_run[2] = {0.f, 0.f};
  const int nkt = (qt + 1) * 2;

  for (int kt = 0; kt < nkt; ++kt) {
    const int k0 = kt * 64;
    __syncthreads();
    {
      const u16* Kt = Kc + ((size_t)bh * 2048 + k0) * 192;
#pragma unroll
      for (int i = 0; i < 6; ++i) {  // K tile: 64 rows x 24 slots
        int seg = t + i * 256;
        int row = seg / 24;
        int sl = seg - row * 24;
        int gsl = sl ^ (row & 7);
        gload16(Kt + (size_t)row * 192 + gsl * 8,
                &Ks[(size_t)(wv * 64 + i * 256) * 8]);
      }
      const u16* Vt = VT + (size_t)bh * 128 * 2048 + k0;
#pragma unroll
      for (int i = 0; i < 4; ++i) {  // V tile: 128 rows x 8 slots
        int seg = t + i * 256;
        int row = seg >> 3;
        int sl = seg & 7;
        int gsl = sl ^ (row & 7);
        gload16(Vt + (size_t)row * 2048 + gsl * 8,
                &Vs[(size_t)(wv * 64 + i * 256) * 8]);
      }
    }
    __syncthreads();
    if (k0 > my_last) continue;  // wave-uniform; barrier count stays aligned
#pragma unroll
    for (int ksub = 0; ksub < 2; ++ksub) {
      const int k0s = k0 + ksub * 32;
      if (k0s > my_last) break;  // wave-uniform, no barriers inside
      floatx4 s00 = fz, s01 = fz, s10 = fz, s11 = fz;  // s{kgrp}{qgrp}
#pragma unroll
      for (int kk = 0; kk < 6; ++kk) {
        int sl0 = ((kk * 4 + g) ^ (qq & 7)) * 8;
        bf16x8 a0 = *(const bf16x8*)&Ks[(ksub * 32 + qq) * 192 + sl0];
        bf16x8 a1 = *(const bf16x8*)&Ks[(ksub * 32 + 16 + qq) * 192 + sl0];
        s00 = MFMA16x16x32(a0, qf[0][kk], s00, 0, 0, 0);
        s10 = MFMA16x16x32(a1, qf[0][kk], s10, 0, 0, 0);
        s01 = MFMA16x16x32(a0, qf[1][kk], s01, 0, 0, 0);
        s11 = MFMA16x16x32(a1, qf[1][kk], s11, 0, 0, 0);
      }
      bf16x8 pf[2];
#pragma unroll
      for (int qg = 0; qg < 2; ++qg) {
        floatx4 sa = qg ? s01 : s00;
        floatx4 sb = qg ? s11 : s10;
        const int q_glob = qrow0 + qg * 16 + qq;
        float v[8];
        float mx = -1e30f;
#pragma unroll
        for (int r = 0; r < 4; ++r) {
          int key0 = k0s + 4 * g + r, key1 = key0 + 16;
          float v0 = sa[r] * SCALE_F, v1 = sb[r] * SCALE_F;
          v0 = (key0 <= q_glob) ? v0 : -1e30f;
          v1 = (key1 <= q_glob) ? v1 : -1e30f;
          v[r] = v0;
          v[4 + r] = v1;
          mx = fmaxf(mx, fmaxf(v0, v1));
        }
        mx = fmaxf(mx, __shfl_xor(mx, 16));
        mx = fmaxf(mx, __shfl_xor(mx, 32));  // per-q-row max (real: key0<=q)
        if (!__all(mx <= m_run[qg] + 8.0f)) {  // defer-max (T13)
          float m_new = fmaxf(m_run[qg], mx);
          float alpha = __expf(m_run[qg] - m_new);
          m_run[qg] = m_new;
          l_run[qg] *= alpha;
          float a4[4];
#pragma unroll
          for (int r = 0; r < 4; ++r) a4[r] = __shfl(alpha, 4 * g + r);
#pragma unroll
          for (int d = 0; d < 8; ++d)
#pragma unroll
            for (int r = 0; r < 4; ++r) oacc[qg][d][r] *= a4[r];
        }
        float sum = 0.f;
        float pex[8];
#pragma unroll
        for (int i = 0; i < 8; ++i) {
          pex[i] = __expf(v[i] - m_run[qg]);
          sum += pex[i];
        }
        sum += __shfl_xor(sum, 16);
        sum += __shfl_xor(sum, 32);
        l_run[qg] += sum;
        u64 w0 = (u64)f2bf(pex[0]) | ((u64)f2bf(pex[1]) << 16) |
                 ((u64)f2bf(pex[2]) << 32) | ((u64)f2bf(pex[3]) << 48);
        u64 w1 = (u64)f2bf(pex[4]) | ((u64)f2bf(pex[5]) << 16) |
                 ((u64)f2bf(pex[6]) << 32) | ((u64)f2bf(pex[7]) << 48);
        *(u64*)&Ps[wv][qq][4 * g] = w0;       // keys 4g..4g+3
        *(u64*)&Ps[wv][qq][16 + 4 * g] = w1;  // keys 16+4g..
        pf[qg] = *(const bf16x8*)&Ps[wv][qq][g * 8];
      }
#pragma unroll
      for (int d = 0; d < 8; ++d) {
        bf16x8 vf = *(const bf16x8*)
            &Vs[(d * 16 + qq) * 64 + (((ksub * 4 + g) ^ (qq & 7)) * 8)];
        oacc[0][d] = MFMA16x16x32(pf[0], vf, oacc[0][d], 0, 0, 0);
        oacc[1][d] = MFMA16x16x32(pf[1], vf, oacc[1][d], 0, 0, 0);
      }
    }
  }
  const int b = bh >> 4, h = bh & 15;
#pragma unroll
  for (int qg = 0; qg < 2; ++qg) {
    float linv = 1.f / l_run[qg];
    float li[4];
#pragma unroll
    for (int r = 0; r < 4; ++r) li[r] = __shfl(linv, 4 * g + r);
#pragma unroll
    for (int d = 0; d < 8; ++d)
#pragma unroll
      for (int r = 0; r < 4; ++r) {
        size_t row = (size_t)b * 2048 + qrow0 + qg * 16 + 4 * g + r;
        O[row * 2048 + h * 128 + d * 16 + qq] = f2bf(oacc[qg][d][r] * li[r]);
      }
  }
}

// ---------------------------------------------------------------------------
extern "C" void kernel_launch(void* const* d_in, const int* in_sizes, int n_in,
                              void* d_out, int out_size, void* d_ws,
                              size_t ws_size, hipStream_t stream) {
  (void)in_sizes; (void)n_in; (void)out_size;
  const float* x = (const float*)d_in[0];
  const float* fc = (const float*)d_in[1];
  const float* wqa = (const float*)d_in[2];
  const float* wqb = (const float*)d_in[3];
  const float* qnw = (const float*)d_in[4];
  const float* wkva = (const float*)d_in[5];
  const float* kvnw = (const float*)d_in[6];
  const float* wkvb = (const float*)d_in[7];
  const float* wo = (const float*)d_in[8];
  float* out = (float*)d_out;
  char* ws = (char*)d_ws;

  size_t off = 0;
  auto alloc = [&](size_t bytes) {
    size_t o = off;
    off += (bytes + 255) & ~(size_t)255;
    return o;
  };
  const size_t o_xbf = alloc(16777216);   // x bf16; later aliased by attn_out
  const size_t o_wqa = alloc(2097152);
  const size_t o_wqb = alloc(3145728);
  const size_t o_wkva = alloc(2359296);
  const size_t o_wkvb = alloc(4194304);
  const size_t o_wo = alloc(8388608);
  const size_t o_qln = alloc(4194304);    // q_lat normed bf16
  const size_t o_kvln = alloc(4194304);   // kv_lat normed bf16
  const size_t o_kpe = alloc(524288);     // roped k_pe bf16
  const size_t o_big = alloc(67108864);   // f32 scratch: qlat/kva -> qfull -> kvb
  const size_t o_qbf = alloc(25165824);   // q packed [bh][s][192]
  const size_t o_kbf = alloc(25165824);   // k packed [bh][s][192]
  const size_t o_vt = alloc(16777216);    // v^T [bh][128][2048]
  if (ws_size < off) return;  // insufficient workspace -> visible failure

  u16* xbf = (u16*)(ws + o_xbf);
  u16* wqab = (u16*)(ws + o_wqa);
  u16* wqbb = (u16*)(ws + o_wqb);
  u16* wkvab = (u16*)(ws + o_wkva);
  u16* wkvbb = (u16*)(ws + o_wkvb);
  u16* wob = (u16*)(ws + o_wo);
  u16* qlatn = (u16*)(ws + o_qln);
  u16* kvlatn = (u16*)(ws + o_kvln);
  u16* kpe = (u16*)(ws + o_kpe);
  float* qlat = (float*)(ws + o_big);               // 4096x512 f32
  float* kva = (float*)(ws + o_big + 8388608);      // 4096x576 f32
  float* qfull = (float*)(ws + o_big);              // 4096x3072 f32 (after kva dead)
  float* kvb = (float*)(ws + o_big);                // 4096x4096 f32 (after qfull dead)
  u16* qbf = (u16*)(ws + o_qbf);
  u16* kbf = (u16*)(ws + o_kbf);
  u16* vt = (u16*)(ws + o_vt);
  u16* attnbf = (u16*)(ws + o_xbf);  // aliases xbf (dead after kv_a GEMM)

  auto cvt = [&](const float* src, u16* dst, int n) {
    int n4 = n / 4;
    int nb = (n4 + 255) / 256;
    if (nb > 2048) nb = 2048;
    cvt_bf16<<<nb, 256, 0, stream>>>(src, dst, n4);
  };
  cvt(x, xbf, 8388608);
  cvt(wqa, wqab, 1048576);
  cvt(wkva, wkvab, 1179648);
  cvt(wqb, wqbb, 1572864);
  cvt(wkvb, wkvbb, 2097152);
  cvt(wo, wob, 4194304);

  // q_lat = x @ wq_a^T ; kv_a = x @ wkv_a^T
  gemm_bt<64><<<dim3(8, 32), 256, 0, stream>>>(xbf, wqab, qlat, 4096, 512, 2048);
  rmsnorm_bf16<<<4096, 256, 0, stream>>>(qlat, 512, qnw, qlatn);
  gemm_bt<64><<<dim3(9, 32), 256, 0, stream>>>(xbf, wkvab, kva, 4096, 576, 2048);
  rope_kpe<<<512, 256, 0, stream>>>(kva, fc, kpe);
  rmsnorm_bf16<<<4096, 256, 0, stream>>>(kva, 576, kvnw, kvlatn);

  // q = rmsnorm(q_lat) @ wq_b^T -> rope+pack
  gemm_bt<128><<<dim3(24, 32), 256, 0, stream>>>(qlatn, wqbb, qfull, 4096, 3072, 512);
  rope_pack_q<<<24576, 256, 0, stream>>>(qfull, fc, qbf);

  // kv = rmsnorm(kv_lat) @ wkv_b^T -> pack k, transpose v
  gemm_bt<128><<<dim3(32, 32), 256, 0, stream>>>(kvlatn, wkvbb, kvb, 4096, 4096, 512);
  pack_k<<<24576, 256, 0, stream>>>(kvb, kpe, kbf);
  transpose_v<<<dim3(64, 4, 32), 256, 0, stream>>>(kvb, vt);

  // attention + output projection
  flash_attn<<<512, 256, 0, stream>>>(qbf, kbf, vt, attnbf);
  gemm_bt<128><<<dim3(16, 32), 256, 0, stream>>>(attnbf, wob, out, 4096, 2048, 2048);
}

// Round 3
// 326.079 us; speedup vs baseline: 1.4893x; 1.1391x over previous
//
#include <hip/hip_runtime.h>
#include <cstdint>
#include <cstddef>

// ---------------------------------------------------------------------------
// MLA forward (B=2, S=2048, DIM=2048, H=16, Q_RANK=KV_RANK=512,
//              D_NOPE=128, D_ROPE=64, D_V=128, D_QK=192)
// Round 3: flash v3 (QBLK=64 -> 1024 blocks, KV=32 double-buffered with
//          counted vmcnt + raw barriers, exp2-domain softmax, mask fast-path,
//          setprio) + merged down-projection GEMM (N=1088).
// ---------------------------------------------------------------------------

typedef unsigned short u16;
typedef unsigned int u32;
typedef unsigned long long u64;
typedef __attribute__((ext_vector_type(8))) short bf16x8;
typedef __attribute__((ext_vector_type(4))) float floatx4;

#define MFMA16x16x32 __builtin_amdgcn_mfma_f32_16x16x32_bf16

// Q is pre-scaled by SCALE * log2(e) so softmax runs in exp2 domain.
#define QSCALE 0.10411755f      // 192^-0.5 * 1.4426950408889634
#define THR_L2 11.541560f       // defer-max threshold 8.0 * log2(e)

__device__ __forceinline__ u16 f2bf(float f) {
  u32 u = __float_as_uint(f);
  u32 r = (u + 0x7fffu + ((u >> 16) & 1u)) >> 16;
  return (u16)r;
}

__device__ __forceinline__ void gload16(const void* g, void* l) {
  __builtin_amdgcn_global_load_lds(
      (const __attribute__((address_space(1))) void*)g,
      (__attribute__((address_space(3))) void*)l, 16, 0, 0);
}

// ---------------- f32 -> bf16 convert (vectorized, grid-stride) -------------
__global__ __launch_bounds__(256) void cvt_bf16(const float* __restrict__ in,
                                                u16* __restrict__ out, int n4) {
  int i = blockIdx.x * 256 + threadIdx.x;
  int stride = gridDim.x * 256;
  for (; i < n4; i += stride) {
    float4 v = ((const float4*)in)[i];
    ushort4 o;
    o.x = f2bf(v.x); o.y = f2bf(v.y); o.z = f2bf(v.z); o.w = f2bf(v.w);
    ((ushort4*)out)[i] = o;
  }
}

// ---------------- GEMM: C(M,N) f32 = A(M,K) bf16 @ B(N,K)^T bf16 ------------
// m97-structure: 128xBN tile, BK=32, 4 waves (2x2), global_load_lds staging
// with slot-XOR swizzle (pre-swizzled source + swizzled ds_read).
template <int BN>
__global__ __launch_bounds__(256) void gemm_bt(const u16* __restrict__ A,
                                               const u16* __restrict__ B,
                                               float* __restrict__ C,
                                               int M, int N, int K) {
  constexpr int FN = BN / 32;
  __shared__ alignas(16) u16 As[128 * 32];
  __shared__ alignas(16) u16 Bs[BN * 32];
  const int m0 = blockIdx.y * 128, n0 = blockIdx.x * BN;
  const int t = threadIdx.x;
  const int wv = t >> 6, lane = t & 63, g = lane >> 4, qq = lane & 15;
  const int wr = wv >> 1, wc = wv & 1;
  const int fsw = (qq >> 1) & 3;  // read-side XOR (row>>1)&3 == (qq>>1)&3
  const floatx4 fz = {0.f, 0.f, 0.f, 0.f};
  floatx4 acc[4][FN];
#pragma unroll
  for (int m = 0; m < 4; ++m)
#pragma unroll
    for (int n = 0; n < FN; ++n) acc[m][n] = fz;

  for (int k0 = 0; k0 < K; k0 += 32) {
    __syncthreads();
#pragma unroll
    for (int i = 0; i < 2; ++i) {  // A tile: 128 rows x 4 slots of 16B
      int seg = t + i * 256;
      int row = seg >> 2, sl = seg & 3;
      int gsl = sl ^ ((row >> 1) & 3);
      gload16(&A[(size_t)(m0 + row) * K + k0 + gsl * 8],
              &As[(size_t)(wv * 64 + i * 256) * 8]);
    }
#pragma unroll
    for (int i = 0; i < BN / 64; ++i) {  // B tile: BN rows x 4 slots
      int seg = t + i * 256;
      int row = seg >> 2, sl = seg & 3;
      int gsl = sl ^ ((row >> 1) & 3);
      gload16(&B[(size_t)(n0 + row) * K + k0 + gsl * 8],
              &Bs[(size_t)(wv * 64 + i * 256) * 8]);
    }
    __syncthreads();
    bf16x8 af[4], bfr[FN];
#pragma unroll
    for (int m = 0; m < 4; ++m)
      af[m] = *(const bf16x8*)&As[(wr * 64 + m * 16 + qq) * 32 + ((g ^ fsw) * 8)];
#pragma unroll
    for (int n = 0; n < FN; ++n)
      bfr[n] = *(const bf16x8*)&Bs[(wc * (BN / 2) + n * 16 + qq) * 32 + ((g ^ fsw) * 8)];
#pragma unroll
    for (int m = 0; m < 4; ++m)
#pragma unroll
      for (int n = 0; n < FN; ++n)
        acc[m][n] = MFMA16x16x32(af[m], bfr[n], acc[m][n], 0, 0, 0);
  }
#pragma unroll
  for (int m = 0; m < 4; ++m)
#pragma unroll
    for (int n = 0; n < FN; ++n)
#pragma unroll
      for (int r = 0; r < 4; ++r) {
        int row = m0 + wr * 64 + m * 16 + 4 * g + r;
        int col = n0 + wc * (BN / 2) + n * 16 + qq;
        C[(size_t)row * N + col] = acc[m][n][r];
      }
}

// ---------------- RMSNorm over 512 cols, f32 in -> bf16 out -----------------
__global__ __launch_bounds__(256) void rmsnorm_bf16(const float* __restrict__ in,
                                                    int stride,
                                                    const float* __restrict__ w,
                                                    u16* __restrict__ out) {
  const int row = blockIdx.x, t = threadIdx.x;
  __shared__ float wsum[4];
  float2 v = *(const float2*)&in[(size_t)row * stride + 2 * t];
  float ss = v.x * v.x + v.y * v.y;
#pragma unroll
  for (int off = 1; off < 64; off <<= 1) ss += __shfl_xor(ss, off);
  if ((t & 63) == 0) wsum[t >> 6] = ss;
  __syncthreads();
  float tot = wsum[0] + wsum[1] + wsum[2] + wsum[3];
  float r = rsqrtf(tot * (1.f / 512.f) + 1e-6f);
  out[(size_t)row * 512 + 2 * t] = f2bf(v.x * r * w[2 * t]);
  out[(size_t)row * 512 + 2 * t + 1] = f2bf(v.y * r * w[2 * t + 1]);
}

// ---------------- RoPE on k_pe (merged proj cols 1024..1087) -> bf16 --------
__global__ __launch_bounds__(256) void rope_kpe(const float* __restrict__ ap,
                                                const float* __restrict__ fc,
                                                u16* __restrict__ kpe) {
  int idx = blockIdx.x * 256 + threadIdx.x;  // 4096*32
  int row = idx >> 5, j = idx & 31;
  int s = row & 2047;
  float xr = ap[(size_t)row * 1088 + 1024 + 2 * j];
  float xi = ap[(size_t)row * 1088 + 1024 + 2 * j + 1];
  float c = fc[(s * 32 + j) * 2], sn = fc[(s * 32 + j) * 2 + 1];
  u32 lo = f2bf(xr * c - xi * sn), hi = f2bf(xr * sn + xi * c);
  *(u32*)&kpe[(size_t)row * 64 + 2 * j] = lo | (hi << 16);
}

// ---------------- RoPE + scale + pack q: -> [bh][s][192] bf16 ---------------
__global__ __launch_bounds__(256) void rope_pack_q(const float* __restrict__ qf,
                                                   const float* __restrict__ fc,
                                                   u16* __restrict__ qbf) {
  int idx = blockIdx.x * 256 + threadIdx.x;  // 4096*16*96
  int j = idx % 96;
  int rh = idx / 96;
  int h = rh & 15, row = rh >> 4;
  int b = row >> 11, s = row & 2047;
  const float* src = qf + (size_t)row * 3072 + h * 192;
  u16* dst = qbf + ((size_t)(b * 16 + h) * 2048 + s) * 192;
  if (j < 64) {
    u32 lo = f2bf(src[2 * j] * QSCALE), hi = f2bf(src[2 * j + 1] * QSCALE);
    *(u32*)&dst[2 * j] = lo | (hi << 16);
  } else {
    int jp = j - 64;
    float xr = src[128 + 2 * jp], xi = src[128 + 2 * jp + 1];
    float c = fc[(s * 32 + jp) * 2], sn = fc[(s * 32 + jp) * 2 + 1];
    u32 lo = f2bf((xr * c - xi * sn) * QSCALE);
    u32 hi = f2bf((xr * sn + xi * c) * QSCALE);
    *(u32*)&dst[128 + 2 * jp] = lo | (hi << 16);
  }
}

// ---------------- pack k: kv_b nope + broadcast k_pe -> [bh][s][192] --------
__global__ __launch_bounds__(256) void pack_k(const float* __restrict__ kvb,
                                              const u16* __restrict__ kpe,
                                              u16* __restrict__ kbf) {
  int idx = blockIdx.x * 256 + threadIdx.x;  // 4096*16*96
  int j = idx % 96;
  int rh = idx / 96;
  int h = rh & 15, row = rh >> 4;
  int b = row >> 11, s = row & 2047;
  u16* dst = kbf + ((size_t)(b * 16 + h) * 2048 + s) * 192;
  if (j < 64) {
    const float* src = kvb + (size_t)row * 4096 + h * 256;
    u32 lo = f2bf(src[2 * j]), hi = f2bf(src[2 * j + 1]);
    *(u32*)&dst[2 * j] = lo | (hi << 16);
  } else {
    int jp = j - 64;
    *(u32*)&dst[128 + 2 * jp] = *(const u32*)&kpe[(size_t)row * 64 + 2 * jp];
  }
}

// ---------------- transpose v: kv_b[...,128:256] -> vt [bh][dv=128][s] ------
__global__ __launch_bounds__(256) void transpose_v(const float* __restrict__ kvb,
                                                   u16* __restrict__ vt) {
  __shared__ u16 T[32][34];
  const int bh = blockIdx.z, b = bh >> 4, h = bh & 15;
  const int s0 = blockIdx.x * 32, d0 = blockIdx.y * 32;
  const int tx = threadIdx.x & 31, ty = threadIdx.x >> 5;
#pragma unroll
  for (int i = 0; i < 4; ++i) {
    int sl = ty + i * 8;
    float v = kvb[(size_t)(b * 2048 + s0 + sl) * 4096 + h * 256 + 128 + d0 + tx];
    T[sl][tx] = f2bf(v);
  }
  __syncthreads();
#pragma unroll
  for (int i = 0; i < 4; ++i) {
    int dl = ty + i * 8;
    vt[((size_t)bh * 128 + d0 + dl) * 2048 + s0 + tx] = T[tx][dl];
  }
}

// ---------------- flash attention v3 ----------------------------------------
// grid 1024 = (qt 32 x bh 32) longest-first; 4 waves x 16 q-rows (QBLK=64);
// KV=32/tile double-buffered: STAGE(next) -> vmcnt(5) -> s_barrier -> compute
// -> s_barrier.  Swapped QK^T, exp2-domain softmax (Q pre-scaled), defer-max,
// mask fast-path, setprio around MFMA clusters.
__global__ __launch_bounds__(256, 3) void flash_attn(const u16* __restrict__ Q,
                                                     const u16* __restrict__ Kc,
                                                     const u16* __restrict__ VT,
                                                     u16* __restrict__ O) {
  __shared__ alignas(16) u16 Ks[2][32 * 192];  // 12 KB each
  __shared__ alignas(16) u16 Vs[2][128 * 32];  // 8 KB each
  __shared__ alignas(16) u16 Ps[4][16][40];    // per-wave P transpose
  const int bid = blockIdx.x;
  const int qt = 31 - (bid >> 5);  // longest blocks first
  const int bh = bid & 31;
  const int t = threadIdx.x, wv = t >> 6, lane = t & 63;
  const int g = lane >> 4, qq = lane & 15;
  const int qrow0 = qt * 64 + wv * 16;
  const int my_last = qrow0 + 15;
  const int q_glob = qrow0 + qq;
  const int nkt = 2 * qt + 2;

  // per-thread staging offsets (u16 units), iteration-invariant
  int koffg[3], voffg[2];
#pragma unroll
  for (int i = 0; i < 3; ++i) {
    int seg = t + i * 256;
    int row = seg / 24, sl = seg - row * 24;
    koffg[i] = row * 192 + (sl ^ (row & 7)) * 8;
  }
#pragma unroll
  for (int i = 0; i < 2; ++i) {
    int seg = t + i * 256;
    int row = seg >> 2, sl = seg & 3;
    voffg[i] = row * 2048 + (sl ^ (row & 3)) * 8;
  }
  const u16* Kt0 = Kc + (size_t)bh * 2048 * 192;
  const u16* Vt0 = VT + (size_t)bh * 128 * 2048;

  bf16x8 qf[6];
  {
    const u16* qp = Q + ((size_t)bh * 2048 + qrow0 + qq) * 192;
#pragma unroll
    for (int kk = 0; kk < 6; ++kk) qf[kk] = *(const bf16x8*)&qp[kk * 32 + g * 8];
  }
  asm volatile("s_waitcnt vmcnt(0)" ::: "memory");  // drain Q before pipeline

  const floatx4 fz = {0.f, 0.f, 0.f, 0.f};
  floatx4 oacc[8];
#pragma unroll
  for (int d = 0; d < 8; ++d) oacc[d] = fz;
  float m_run = -1e30f, l_run = 0.f;

#define STAGE(buf, kt)                                                       \
  {                                                                          \
    const u16* Kg = Kt0 + (size_t)(kt) * (32 * 192);                         \
    const u16* Vg = Vt0 + (kt) * 32;                                         \
    _Pragma("unroll") for (int i = 0; i < 3; ++i)                            \
        gload16(Kg + koffg[i], &Ks[buf][(size_t)(wv * 64 + i * 256) * 8]);   \
    _Pragma("unroll") for (int i = 0; i < 2; ++i)                            \
        gload16(Vg + voffg[i], &Vs[buf][(size_t)(wv * 64 + i * 256) * 8]);   \
  }

  STAGE(0, 0);
  for (int kt = 0; kt < nkt; ++kt) {
    const int k0 = kt * 32;
    asm volatile("" ::: "memory");
    if (kt + 1 < nkt) {
      STAGE((kt + 1) & 1, kt + 1);
      asm volatile("s_waitcnt vmcnt(5)" ::: "memory");
    } else {
      asm volatile("s_waitcnt vmcnt(0)" ::: "memory");
    }
    __builtin_amdgcn_s_barrier();
    asm volatile("" ::: "memory");
    if (k0 <= my_last) {  // wave-uniform
      const u16* Kb = &Ks[kt & 1][0];
      const u16* Vb = &Vs[kt & 1][0];
      floatx4 s0 = fz, s1 = fz;
      __builtin_amdgcn_s_setprio(1);
#pragma unroll
      for (int kk = 0; kk < 6; ++kk) {
        int sl0 = ((kk * 4 + g) ^ (qq & 7)) * 8;
        bf16x8 a0 = *(const bf16x8*)&Kb[qq * 192 + sl0];
        bf16x8 a1 = *(const bf16x8*)&Kb[(16 + qq) * 192 + sl0];
        s0 = MFMA16x16x32(a0, qf[kk], s0, 0, 0, 0);
        s1 = MFMA16x16x32(a1, qf[kk], s1, 0, 0, 0);
      }
      __builtin_amdgcn_s_setprio(0);
      float v[8];
      if (k0 + 31 <= qrow0) {  // fully-unmasked fast path (wave-uniform)
#pragma unroll
        for (int r = 0; r < 4; ++r) {
          v[r] = s0[r];
          v[4 + r] = s1[r];
        }
      } else {
#pragma unroll
        for (int r = 0; r < 4; ++r) {
          int key0 = k0 + 4 * g + r;
          v[r] = (key0 <= q_glob) ? s0[r] : -1e30f;
          v[4 + r] = (key0 + 16 <= q_glob) ? s1[r] : -1e30f;
        }
      }
      float mx = fmaxf(fmaxf(fmaxf(v[0], v[1]), fmaxf(v[2], v[3])),
                       fmaxf(fmaxf(v[4], v[5]), fmaxf(v[6], v[7])));
      mx = fmaxf(mx, __shfl_xor(mx, 16));
      mx = fmaxf(mx, __shfl_xor(mx, 32));
      if (!__all(mx <= m_run + THR_L2)) {  // defer-max (T13)
        float m_new = fmaxf(m_run, mx);
        float alpha = exp2f(m_run - m_new);
        m_run = m_new;
        l_run *= alpha;
        float a4[4];
#pragma unroll
        for (int r = 0; r < 4; ++r) a4[r] = __shfl(alpha, 4 * g + r);
#pragma unroll
        for (int d = 0; d < 8; ++d)
#pragma unroll
          for (int r = 0; r < 4; ++r) oacc[d][r] *= a4[r];
      }
      float pex[8], sum = 0.f;
#pragma unroll
      for (int i = 0; i < 8; ++i) {
        pex[i] = exp2f(v[i] - m_run);
        sum += pex[i];
      }
      sum += __shfl_xor(sum, 16);
      sum += __shfl_xor(sum, 32);
      l_run += sum;
      u64 w0 = (u64)f2bf(pex[0]) | ((u64)f2bf(pex[1]) << 16) |
               ((u64)f2bf(pex[2]) << 32) | ((u64)f2bf(pex[3]) << 48);
      u64 w1 = (u64)f2bf(pex[4]) | ((u64)f2bf(pex[5]) << 16) |
               ((u64)f2bf(pex[6]) << 32) | ((u64)f2bf(pex[7]) << 48);
      *(u64*)&Ps[wv][qq][4 * g] = w0;
      *(u64*)&Ps[wv][qq][16 + 4 * g] = w1;
      bf16x8 pf = *(const bf16x8*)&Ps[wv][qq][g * 8];
      __builtin_amdgcn_s_setprio(1);
#pragma unroll
      for (int d = 0; d < 8; ++d) {
        bf16x8 vf = *(const bf16x8*)&Vb[(d * 16 + qq) * 32 + ((g ^ (qq & 3)) * 8)];
        oacc[d] = MFMA16x16x32(pf, vf, oacc[d], 0, 0, 0);
      }
      __builtin_amdgcn_s_setprio(0);
    }
    asm volatile("" ::: "memory");
    __builtin_amdgcn_s_barrier();
  }
#undef STAGE
  float linv = 1.f / l_run;
  float li[4];
#pragma unroll
  for (int r = 0; r < 4; ++r) li[r] = __shfl(linv, 4 * g + r);
  const int b = bh >> 4, h = bh & 15;
#pragma unroll
  for (int d = 0; d < 8; ++d)
#pragma unroll
    for (int r = 0; r < 4; ++r) {
      size_t row = (size_t)b * 2048 + qrow0 + 4 * g + r;
      O[row * 2048 + h * 128 + d * 16 + qq] = f2bf(oacc[d][r] * li[r]);
    }
}

// ---------------------------------------------------------------------------
extern "C" void kernel_launch(void* const* d_in, const int* in_sizes, int n_in,
                              void* d_out, int out_size, void* d_ws,
                              size_t ws_size, hipStream_t stream) {
  (void)in_sizes; (void)n_in; (void)out_size;
  const float* x = (const float*)d_in[0];
  const float* fc = (const float*)d_in[1];
  const float* wqa = (const float*)d_in[2];
  const float* wqb = (const float*)d_in[3];
  const float* qnw = (const float*)d_in[4];
  const float* wkva = (const float*)d_in[5];
  const float* kvnw = (const float*)d_in[6];
  const float* wkvb = (const float*)d_in[7];
  const float* wo = (const float*)d_in[8];
  float* out = (float*)d_out;
  char* ws = (char*)d_ws;

  size_t off = 0;
  auto alloc = [&](size_t bytes) {
    size_t o = off;
    off += (bytes + 255) & ~(size_t)255;
    return o;
  };
  const size_t o_xbf = alloc(16777216);   // x bf16; later aliased by attn_out
  const size_t o_wa = alloc(4456448);     // merged [wq_a;wkv_a] bf16 (1088x2048)
  const size_t o_wqb = alloc(3145728);
  const size_t o_wkvb = alloc(4194304);
  const size_t o_wo = alloc(8388608);
  const size_t o_qln = alloc(4194304);    // q_lat normed bf16
  const size_t o_kvln = alloc(4194304);   // kv_lat normed bf16
  const size_t o_kpe = alloc(524288);     // roped k_pe bf16
  const size_t o_big = alloc(67108864);   // f32: aproj -> qfull -> kvb
  const size_t o_qbf = alloc(25165824);   // q packed [bh][s][192] (pre-scaled)
  const size_t o_kbf = alloc(25165824);   // k packed [bh][s][192]
  const size_t o_vt = alloc(16777216);    // v^T [bh][128][2048]
  if (ws_size < off) return;

  u16* xbf = (u16*)(ws + o_xbf);
  u16* wab = (u16*)(ws + o_wa);           // rows 0..511 wq_a, 512..1087 wkv_a
  u16* wqbb = (u16*)(ws + o_wqb);
  u16* wkvbb = (u16*)(ws + o_wkvb);
  u16* wob = (u16*)(ws + o_wo);
  u16* qlatn = (u16*)(ws + o_qln);
  u16* kvlatn = (u16*)(ws + o_kvln);
  u16* kpe = (u16*)(ws + o_kpe);
  float* aproj = (float*)(ws + o_big);    // 4096x1088 f32
  float* qfull = (float*)(ws + o_big);    // 4096x3072 f32 (after aproj dead)
  float* kvb = (float*)(ws + o_big);      // 4096x4096 f32 (after qfull dead)
  u16* qbf = (u16*)(ws + o_qbf);
  u16* kbf = (u16*)(ws + o_kbf);
  u16* vt = (u16*)(ws + o_vt);
  u16* attnbf = (u16*)(ws + o_xbf);       // aliases xbf (dead after aproj)

  auto cvt = [&](const float* src, u16* dst, int n) {
    int n4 = n / 4;
    int nb = (n4 + 255) / 256;
    if (nb > 2048) nb = 2048;
    cvt_bf16<<<nb, 256, 0, stream>>>(src, dst, n4);
  };
  cvt(x, xbf, 8388608);
  cvt(wqa, wab, 1048576);                  // rows 0..511
  cvt(wkva, (u16*)(ws + o_wa) + 1048576, 1179648);  // rows 512..1087
  cvt(wqb, wqbb, 1572864);
  cvt(wkvb, wkvbb, 2097152);
  cvt(wo, wob, 4194304);

  // merged down-projection: [q_lat | kv_lat | k_pe] = x @ [wq_a;wkv_a]^T
  gemm_bt<64><<<dim3(17, 32), 256, 0, stream>>>(xbf, wab, aproj, 4096, 1088, 2048);
  rmsnorm_bf16<<<4096, 256, 0, stream>>>(aproj, 1088, qnw, qlatn);
  rmsnorm_bf16<<<4096, 256, 0, stream>>>(aproj + 512, 1088, kvnw, kvlatn);
  rope_kpe<<<512, 256, 0, stream>>>(aproj, fc, kpe);

  // q = rmsnorm(q_lat) @ wq_b^T -> rope+scale+pack
  gemm_bt<128><<<dim3(24, 32), 256, 0, stream>>>(qlatn, wqbb, qfull, 4096, 3072, 512);
  rope_pack_q<<<24576, 256, 0, stream>>>(qfull, fc, qbf);

  // kv = rmsnorm(kv_lat) @ wkv_b^T -> pack k, transpose v
  gemm_bt<128><<<dim3(32, 32), 256, 0, stream>>>(kvlatn, wkvbb, kvb, 4096, 4096, 512);
  pack_k<<<24576, 256, 0, stream>>>(kvb, kpe, kbf);
  transpose_v<<<dim3(64, 4, 32), 256, 0, stream>>>(kvb, vt);

  // attention + output projection
  flash_attn<<<1024, 256, 0, stream>>>(qbf, kbf, vt, attnbf);
  gemm_bt<128><<<dim3(16, 32), 256, 0, stream>>>(attnbf, wob, out, 4096, 2048, 2048);
}

// Round 4
// 318.625 us; speedup vs baseline: 1.5242x; 1.0234x over previous
//
#include <hip/hip_runtime.h>
#include <cstdint>
#include <cstddef>

// ---------------------------------------------------------------------------
// MLA forward (B=2, S=2048, DIM=2048, H=16, Q_RANK=KV_RANK=512,
//              D_NOPE=128, D_ROPE=64, D_V=128, D_QK=192)
// Round 4: flash v4 (fixed V swizzle (row>>1)&3, P->A-frag via shfl_b64 (no
//          Ps LDS -> 40KB -> 4 blocks/CU)) + GEMM v2 (double-buffered LDS,
//          counted vmcnt, raw barriers — flash-proven schedule).
// ---------------------------------------------------------------------------

typedef unsigned short u16;
typedef unsigned int u32;
typedef unsigned long long u64;
typedef __attribute__((ext_vector_type(8))) short bf16x8;
typedef __attribute__((ext_vector_type(4))) float floatx4;

#define MFMA16x16x32 __builtin_amdgcn_mfma_f32_16x16x32_bf16

// Q is pre-scaled by SCALE * log2(e) so softmax runs in exp2 domain.
#define QSCALE 0.10411755f      // 192^-0.5 * 1.4426950408889634
#define THR_L2 11.541560f       // defer-max threshold 8.0 * log2(e)

__device__ __forceinline__ u16 f2bf(float f) {
  u32 u = __float_as_uint(f);
  u32 r = (u + 0x7fffu + ((u >> 16) & 1u)) >> 16;
  return (u16)r;
}

__device__ __forceinline__ void gload16(const void* g, void* l) {
  __builtin_amdgcn_global_load_lds(
      (const __attribute__((address_space(1))) void*)g,
      (__attribute__((address_space(3))) void*)l, 16, 0, 0);
}

// ---------------- f32 -> bf16 convert (vectorized, grid-stride) -------------
__global__ __launch_bounds__(256) void cvt_bf16(const float* __restrict__ in,
                                                u16* __restrict__ out, int n4) {
  int i = blockIdx.x * 256 + threadIdx.x;
  int stride = gridDim.x * 256;
  for (; i < n4; i += stride) {
    float4 v = ((const float4*)in)[i];
    ushort4 o;
    o.x = f2bf(v.x); o.y = f2bf(v.y); o.z = f2bf(v.z); o.w = f2bf(v.w);
    ((ushort4*)out)[i] = o;
  }
}

// ---------------- GEMM v2: C(M,N) f32 = A(M,K) bf16 @ B(N,K)^T bf16 ---------
// 128xBN tile, BK=32, 4 waves (2x2). Double-buffered LDS; per K-step:
// STAGE(next,buf^1) -> s_waitcnt vmcnt(L) -> s_barrier -> compute(buf) ->
// s_barrier. gload_lds staging with slot-XOR swizzle (pre-swizzled source).
template <int BN>
__global__ __launch_bounds__(256) void gemm_bt(const u16* __restrict__ A,
                                               const u16* __restrict__ B,
                                               float* __restrict__ C,
                                               int M, int N, int K) {
  constexpr int FN = BN / 32;
  constexpr int BL = BN / 64;
  __shared__ alignas(16) u16 As[2][128 * 32];
  __shared__ alignas(16) u16 Bs[2][BN * 32];
  const int m0 = blockIdx.y * 128, n0 = blockIdx.x * BN;
  const int t = threadIdx.x;
  const int wv = t >> 6, lane = t & 63, g = lane >> 4, qq = lane & 15;
  const int wr = wv >> 1, wc = wv & 1;
  const int fsw = (qq >> 1) & 3;  // read-side XOR == (row>>1)&3
  // per-thread global element offsets (k0 added per step)
  size_t aoff[2], boff[BL];
#pragma unroll
  for (int i = 0; i < 2; ++i) {
    int seg = t + i * 256;
    int row = seg >> 2, sl = seg & 3;
    aoff[i] = (size_t)(m0 + row) * K + (sl ^ ((row >> 1) & 3)) * 8;
  }
#pragma unroll
  for (int i = 0; i < BL; ++i) {
    int seg = t + i * 256;
    int row = seg >> 2, sl = seg & 3;
    boff[i] = (size_t)(n0 + row) * K + (sl ^ ((row >> 1) & 3)) * 8;
  }
  const floatx4 fz = {0.f, 0.f, 0.f, 0.f};
  floatx4 acc[4][FN];
#pragma unroll
  for (int m = 0; m < 4; ++m)
#pragma unroll
    for (int n = 0; n < FN; ++n) acc[m][n] = fz;

#define GSTAGE(buf, k0)                                                      \
  {                                                                          \
    _Pragma("unroll") for (int i = 0; i < 2; ++i)                            \
        gload16(&A[aoff[i] + (k0)], &As[buf][(size_t)(wv * 64 + i * 256) * 8]); \
    _Pragma("unroll") for (int i = 0; i < BL; ++i)                           \
        gload16(&B[boff[i] + (k0)], &Bs[buf][(size_t)(wv * 64 + i * 256) * 8]); \
  }

  const int nk = K >> 5;
  GSTAGE(0, 0);
  for (int kt = 0; kt < nk; ++kt) {
    asm volatile("" ::: "memory");
    if (kt + 1 < nk) {
      GSTAGE((kt + 1) & 1, (kt + 1) * 32);
      if constexpr (BN == 128)
        asm volatile("s_waitcnt vmcnt(4)" ::: "memory");
      else
        asm volatile("s_waitcnt vmcnt(3)" ::: "memory");
    } else {
      asm volatile("s_waitcnt vmcnt(0)" ::: "memory");
    }
    __builtin_amdgcn_s_barrier();
    asm volatile("" ::: "memory");
    const u16* Ab = &As[kt & 1][0];
    const u16* Bb = &Bs[kt & 1][0];
    bf16x8 af[4], bfr[FN];
#pragma unroll
    for (int m = 0; m < 4; ++m)
      af[m] = *(const bf16x8*)&Ab[(wr * 64 + m * 16 + qq) * 32 + ((g ^ fsw) * 8)];
#pragma unroll
    for (int n = 0; n < FN; ++n)
      bfr[n] = *(const bf16x8*)&Bb[(wc * (BN / 2) + n * 16 + qq) * 32 + ((g ^ fsw) * 8)];
    __builtin_amdgcn_s_setprio(1);
#pragma unroll
    for (int m = 0; m < 4; ++m)
#pragma unroll
      for (int n = 0; n < FN; ++n)
        acc[m][n] = MFMA16x16x32(af[m], bfr[n], acc[m][n], 0, 0, 0);
    __builtin_amdgcn_s_setprio(0);
    asm volatile("" ::: "memory");
    __builtin_amdgcn_s_barrier();
  }
#undef GSTAGE
#pragma unroll
  for (int m = 0; m < 4; ++m)
#pragma unroll
    for (int n = 0; n < FN; ++n)
#pragma unroll
      for (int r = 0; r < 4; ++r) {
        int row = m0 + wr * 64 + m * 16 + 4 * g + r;
        int col = n0 + wc * (BN / 2) + n * 16 + qq;
        C[(size_t)row * N + col] = acc[m][n][r];
      }
}

// ---------------- RMSNorm over 512 cols, f32 in -> bf16 out -----------------
__global__ __launch_bounds__(256) void rmsnorm_bf16(const float* __restrict__ in,
                                                    int stride,
                                                    const float* __restrict__ w,
                                                    u16* __restrict__ out) {
  const int row = blockIdx.x, t = threadIdx.x;
  __shared__ float wsum[4];
  float2 v = *(const float2*)&in[(size_t)row * stride + 2 * t];
  float ss = v.x * v.x + v.y * v.y;
#pragma unroll
  for (int off = 1; off < 64; off <<= 1) ss += __shfl_xor(ss, off);
  if ((t & 63) == 0) wsum[t >> 6] = ss;
  __syncthreads();
  float tot = wsum[0] + wsum[1] + wsum[2] + wsum[3];
  float r = rsqrtf(tot * (1.f / 512.f) + 1e-6f);
  out[(size_t)row * 512 + 2 * t] = f2bf(v.x * r * w[2 * t]);
  out[(size_t)row * 512 + 2 * t + 1] = f2bf(v.y * r * w[2 * t + 1]);
}

// ---------------- RoPE on k_pe (merged proj cols 1024..1087) -> bf16 --------
__global__ __launch_bounds__(256) void rope_kpe(const float* __restrict__ ap,
                                                const float* __restrict__ fc,
                                                u16* __restrict__ kpe) {
  int idx = blockIdx.x * 256 + threadIdx.x;  // 4096*32
  int row = idx >> 5, j = idx & 31;
  int s = row & 2047;
  float xr = ap[(size_t)row * 1088 + 1024 + 2 * j];
  float xi = ap[(size_t)row * 1088 + 1024 + 2 * j + 1];
  float c = fc[(s * 32 + j) * 2], sn = fc[(s * 32 + j) * 2 + 1];
  u32 lo = f2bf(xr * c - xi * sn), hi = f2bf(xr * sn + xi * c);
  *(u32*)&kpe[(size_t)row * 64 + 2 * j] = lo | (hi << 16);
}

// ---------------- RoPE + scale + pack q: -> [bh][s][192] bf16 ---------------
__global__ __launch_bounds__(256) void rope_pack_q(const float* __restrict__ qf,
                                                   const float* __restrict__ fc,
                                                   u16* __restrict__ qbf) {
  int idx = blockIdx.x * 256 + threadIdx.x;  // 4096*16*96
  int j = idx % 96;
  int rh = idx / 96;
  int h = rh & 15, row = rh >> 4;
  int b = row >> 11, s = row & 2047;
  const float* src = qf + (size_t)row * 3072 + h * 192;
  u16* dst = qbf + ((size_t)(b * 16 + h) * 2048 + s) * 192;
  if (j < 64) {
    u32 lo = f2bf(src[2 * j] * QSCALE), hi = f2bf(src[2 * j + 1] * QSCALE);
    *(u32*)&dst[2 * j] = lo | (hi << 16);
  } else {
    int jp = j - 64;
    float xr = src[128 + 2 * jp], xi = src[128 + 2 * jp + 1];
    float c = fc[(s * 32 + jp) * 2], sn = fc[(s * 32 + jp) * 2 + 1];
    u32 lo = f2bf((xr * c - xi * sn) * QSCALE);
    u32 hi = f2bf((xr * sn + xi * c) * QSCALE);
    *(u32*)&dst[128 + 2 * jp] = lo | (hi << 16);
  }
}

// ---------------- pack k: kv_b nope + broadcast k_pe -> [bh][s][192] --------
__global__ __launch_bounds__(256) void pack_k(const float* __restrict__ kvb,
                                              const u16* __restrict__ kpe,
                                              u16* __restrict__ kbf) {
  int idx = blockIdx.x * 256 + threadIdx.x;  // 4096*16*96
  int j = idx % 96;
  int rh = idx / 96;
  int h = rh & 15, row = rh >> 4;
  int b = row >> 11, s = row & 2047;
  u16* dst = kbf + ((size_t)(b * 16 + h) * 2048 + s) * 192;
  if (j < 64) {
    const float* src = kvb + (size_t)row * 4096 + h * 256;
    u32 lo = f2bf(src[2 * j]), hi = f2bf(src[2 * j + 1]);
    *(u32*)&dst[2 * j] = lo | (hi << 16);
  } else {
    int jp = j - 64;
    *(u32*)&dst[128 + 2 * jp] = *(const u32*)&kpe[(size_t)row * 64 + 2 * jp];
  }
}

// ---------------- transpose v: kv_b[...,128:256] -> vt [bh][dv=128][s] ------
__global__ __launch_bounds__(256) void transpose_v(const float* __restrict__ kvb,
                                                   u16* __restrict__ vt) {
  __shared__ u16 T[32][34];
  const int bh = blockIdx.z, b = bh >> 4, h = bh & 15;
  const int s0 = blockIdx.x * 32, d0 = blockIdx.y * 32;
  const int tx = threadIdx.x & 31, ty = threadIdx.x >> 5;
#pragma unroll
  for (int i = 0; i < 4; ++i) {
    int sl = ty + i * 8;
    float v = kvb[(size_t)(b * 2048 + s0 + sl) * 4096 + h * 256 + 128 + d0 + tx];
    T[sl][tx] = f2bf(v);
  }
  __syncthreads();
#pragma unroll
  for (int i = 0; i < 4; ++i) {
    int dl = ty + i * 8;
    vt[((size_t)bh * 128 + d0 + dl) * 2048 + s0 + tx] = T[tx][dl];
  }
}

// ---------------- flash attention v4 ----------------------------------------
// grid 1024 = (qt 32 x bh 32) longest-first; 4 waves x 16 q-rows (QBLK=64);
// KV=32/tile double-buffered, counted vmcnt(5). Swapped QK^T, exp2-domain
// softmax, defer-max, mask fast-path, setprio. P->A-frag via 4x shfl_b64
// (no LDS P buffer -> 40KB LDS -> 4 blocks/CU).
__global__ __launch_bounds__(256, 4) void flash_attn(const u16* __restrict__ Q,
                                                     const u16* __restrict__ Kc,
                                                     const u16* __restrict__ VT,
                                                     u16* __restrict__ O) {
  __shared__ alignas(16) u16 Ks[2][32 * 192];  // 12 KB each
  __shared__ alignas(16) u16 Vs[2][128 * 32];  // 8 KB each
  const int bid = blockIdx.x;
  const int qt = 31 - (bid >> 5);  // longest blocks first
  const int bh = bid & 31;
  const int t = threadIdx.x, wv = t >> 6, lane = t & 63;
  const int g = lane >> 4, qq = lane & 15;
  const int qrow0 = qt * 64 + wv * 16;
  const int my_last = qrow0 + 15;
  const int q_glob = qrow0 + qq;
  const int nkt = 2 * qt + 2;

  // per-thread staging offsets (u16 units), iteration-invariant
  int koffg[3], voffg[2];
#pragma unroll
  for (int i = 0; i < 3; ++i) {
    int seg = t + i * 256;
    int row = seg / 24, sl = seg - row * 24;
    koffg[i] = row * 192 + (sl ^ (row & 7)) * 8;
  }
#pragma unroll
  for (int i = 0; i < 2; ++i) {
    int seg = t + i * 256;
    int row = seg >> 2, sl = seg & 3;
    voffg[i] = row * 2048 + (sl ^ ((row >> 1) & 3)) * 8;  // fixed: (row>>1)&3
  }
  const u16* Kt0 = Kc + (size_t)bh * 2048 * 192;
  const u16* Vt0 = VT + (size_t)bh * 128 * 2048;

  bf16x8 qf[6];
  {
    const u16* qp = Q + ((size_t)bh * 2048 + qrow0 + qq) * 192;
#pragma unroll
    for (int kk = 0; kk < 6; ++kk) qf[kk] = *(const bf16x8*)&qp[kk * 32 + g * 8];
  }
  asm volatile("s_waitcnt vmcnt(0)" ::: "memory");  // drain Q before pipeline

  const floatx4 fz = {0.f, 0.f, 0.f, 0.f};
  floatx4 oacc[8];
#pragma unroll
  for (int d = 0; d < 8; ++d) oacc[d] = fz;
  float m_run = -1e30f, l_run = 0.f;

  // P->A-frag shuffle sources (iteration-invariant)
  const int src_lo = qq + 16 * ((2 * g) & 3);
  const int src_hi = qq + 16 * ((2 * g + 1) & 3);

#define STAGE(buf, kt)                                                       \
  {                                                                          \
    const u16* Kg = Kt0 + (size_t)(kt) * (32 * 192);                         \
    const u16* Vg = Vt0 + (kt) * 32;                                         \
    _Pragma("unroll") for (int i = 0; i < 3; ++i)                            \
        gload16(Kg + koffg[i], &Ks[buf][(size_t)(wv * 64 + i * 256) * 8]);   \
    _Pragma("unroll") for (int i = 0; i < 2; ++i)                            \
        gload16(Vg + voffg[i], &Vs[buf][(size_t)(wv * 64 + i * 256) * 8]);   \
  }

  STAGE(0, 0);
  for (int kt = 0; kt < nkt; ++kt) {
    const int k0 = kt * 32;
    asm volatile("" ::: "memory");
    if (kt + 1 < nkt) {
      STAGE((kt + 1) & 1, kt + 1);
      asm volatile("s_waitcnt vmcnt(5)" ::: "memory");
    } else {
      asm volatile("s_waitcnt vmcnt(0)" ::: "memory");
    }
    __builtin_amdgcn_s_barrier();
    asm volatile("" ::: "memory");
    if (k0 <= my_last) {  // wave-uniform
      const u16* Kb = &Ks[kt & 1][0];
      const u16* Vb = &Vs[kt & 1][0];
      floatx4 s0 = fz, s1 = fz;
      __builtin_amdgcn_s_setprio(1);
#pragma unroll
      for (int kk = 0; kk < 6; ++kk) {
        int sl0 = ((kk * 4 + g) ^ (qq & 7)) * 8;
        bf16x8 a0 = *(const bf16x8*)&Kb[qq * 192 + sl0];
        bf16x8 a1 = *(const bf16x8*)&Kb[(16 + qq) * 192 + sl0];
        s0 = MFMA16x16x32(a0, qf[kk], s0, 0, 0, 0);
        s1 = MFMA16x16x32(a1, qf[kk], s1, 0, 0, 0);
      }
      __builtin_amdgcn_s_setprio(0);
      float v[8];
      if (k0 + 31 <= qrow0) {  // fully-unmasked fast path (wave-uniform)
#pragma unroll
        for (int r = 0; r < 4; ++r) {
          v[r] = s0[r];
          v[4 + r] = s1[r];
        }
      } else {
#pragma unroll
        for (int r = 0; r < 4; ++r) {
          int key0 = k0 + 4 * g + r;
          v[r] = (key0 <= q_glob) ? s0[r] : -1e30f;
          v[4 + r] = (key0 + 16 <= q_glob) ? s1[r] : -1e30f;
        }
      }
      float mx = fmaxf(fmaxf(fmaxf(v[0], v[1]), fmaxf(v[2], v[3])),
                       fmaxf(fmaxf(v[4], v[5]), fmaxf(v[6], v[7])));
      mx = fmaxf(mx, __shfl_xor(mx, 16));
      mx = fmaxf(mx, __shfl_xor(mx, 32));
      if (!__all(mx <= m_run + THR_L2)) {  // defer-max (T13)
        float m_new = fmaxf(m_run, mx);
        float alpha = exp2f(m_run - m_new);
        m_run = m_new;
        l_run *= alpha;
        float a4[4];
#pragma unroll
        for (int r = 0; r < 4; ++r) a4[r] = __shfl(alpha, 4 * g + r);
#pragma unroll
        for (int d = 0; d < 8; ++d)
#pragma unroll
          for (int r = 0; r < 4; ++r) oacc[d][r] *= a4[r];
      }
      float pex[8], sum = 0.f;
#pragma unroll
      for (int i = 0; i < 8; ++i) {
        pex[i] = exp2f(v[i] - m_run);
        sum += pex[i];
      }
      sum += __shfl_xor(sum, 16);
      sum += __shfl_xor(sum, 32);
      l_run += sum;
      // pack P and permute to A-fragment layout in-register:
      // lane(qq,g) holds keys {4g..4g+3} (w0), {16+4g..19+4g} (w1);
      // A-frag needs keys {8g..8g+7} = two u64s from lanes src_lo/src_hi.
      u64 w0 = (u64)f2bf(pex[0]) | ((u64)f2bf(pex[1]) << 16) |
               ((u64)f2bf(pex[2]) << 32) | ((u64)f2bf(pex[3]) << 48);
      u64 w1 = (u64)f2bf(pex[4]) | ((u64)f2bf(pex[5]) << 16) |
               ((u64)f2bf(pex[6]) << 32) | ((u64)f2bf(pex[7]) << 48);
      u64 a0 = (u64)__shfl((long long)w0, src_lo);
      u64 a1 = (u64)__shfl((long long)w1, src_lo);
      u64 b0 = (u64)__shfl((long long)w0, src_hi);
      u64 b1 = (u64)__shfl((long long)w1, src_hi);
      bf16x8 pf;
      ((u64*)&pf)[0] = (g < 2) ? a0 : a1;
      ((u64*)&pf)[1] = (g < 2) ? b0 : b1;
      __builtin_amdgcn_s_setprio(1);
#pragma unroll
      for (int d = 0; d < 8; ++d) {
        bf16x8 vf = *(const bf16x8*)
            &Vb[(d * 16 + qq) * 32 + ((g ^ ((qq >> 1) & 3)) * 8)];
        oacc[d] = MFMA16x16x32(pf, vf, oacc[d], 0, 0, 0);
      }
      __builtin_amdgcn_s_setprio(0);
    }
    asm volatile("" ::: "memory");
    __builtin_amdgcn_s_barrier();
  }
#undef STAGE
  float linv = 1.f / l_run;
  float li[4];
#pragma unroll
  for (int r = 0; r < 4; ++r) li[r] = __shfl(linv, 4 * g + r);
  const int b = bh >> 4, h = bh & 15;
#pragma unroll
  for (int d = 0; d < 8; ++d)
#pragma unroll
    for (int r = 0; r < 4; ++r) {
      size_t row = (size_t)b * 2048 + qrow0 + 4 * g + r;
      O[row * 2048 + h * 128 + d * 16 + qq] = f2bf(oacc[d][r] * li[r]);
    }
}

// ---------------------------------------------------------------------------
extern "C" void kernel_launch(void* const* d_in, const int* in_sizes, int n_in,
                              void* d_out, int out_size, void* d_ws,
                              size_t ws_size, hipStream_t stream) {
  (void)in_sizes; (void)n_in; (void)out_size;
  const float* x = (const float*)d_in[0];
  const float* fc = (const float*)d_in[1];
  const float* wqa = (const float*)d_in[2];
  const float* wqb = (const float*)d_in[3];
  const float* qnw = (const float*)d_in[4];
  const float* wkva = (const float*)d_in[5];
  const float* kvnw = (const float*)d_in[6];
  const float* wkvb = (const float*)d_in[7];
  const float* wo = (const float*)d_in[8];
  float* out = (float*)d_out;
  char* ws = (char*)d_ws;

  size_t off = 0;
  auto alloc = [&](size_t bytes) {
    size_t o = off;
    off += (bytes + 255) & ~(size_t)255;
    return o;
  };
  const size_t o_xbf = alloc(16777216);   // x bf16; later aliased by attn_out
  const size_t o_wa = alloc(4456448);     // merged [wq_a;wkv_a] bf16 (1088x2048)
  const size_t o_wqb = alloc(3145728);
  const size_t o_wkvb = alloc(4194304);
  const size_t o_wo = alloc(8388608);
  const size_t o_qln = alloc(4194304);    // q_lat normed bf16
  const size_t o_kvln = alloc(4194304);   // kv_lat normed bf16
  const size_t o_kpe = alloc(524288);     // roped k_pe bf16
  const size_t o_big = alloc(67108864);   // f32: aproj -> qfull -> kvb
  const size_t o_qbf = alloc(25165824);   // q packed [bh][s][192] (pre-scaled)
  const size_t o_kbf = alloc(25165824);   // k packed [bh][s][192]
  const size_t o_vt = alloc(16777216);    // v^T [bh][128][2048]
  if (ws_size < off) return;

  u16* xbf = (u16*)(ws + o_xbf);
  u16* wab = (u16*)(ws + o_wa);           // rows 0..511 wq_a, 512..1087 wkv_a
  u16* wqbb = (u16*)(ws + o_wqb);
  u16* wkvbb = (u16*)(ws + o_wkvb);
  u16* wob = (u16*)(ws + o_wo);
  u16* qlatn = (u16*)(ws + o_qln);
  u16* kvlatn = (u16*)(ws + o_kvln);
  u16* kpe = (u16*)(ws + o_kpe);
  float* aproj = (float*)(ws + o_big);    // 4096x1088 f32
  float* qfull = (float*)(ws + o_big);    // 4096x3072 f32 (after aproj dead)
  float* kvb = (float*)(ws + o_big);      // 4096x4096 f32 (after qfull dead)
  u16* qbf = (u16*)(ws + o_qbf);
  u16* kbf = (u16*)(ws + o_kbf);
  u16* vt = (u16*)(ws + o_vt);
  u16* attnbf = (u16*)(ws + o_xbf);       // aliases xbf (dead after aproj)

  auto cvt = [&](const float* src, u16* dst, int n) {
    int n4 = n / 4;
    int nb = (n4 + 255) / 256;
    if (nb > 2048) nb = 2048;
    cvt_bf16<<<nb, 256, 0, stream>>>(src, dst, n4);
  };
  cvt(x, xbf, 8388608);
  cvt(wqa, wab, 1048576);                  // rows 0..511
  cvt(wkva, (u16*)(ws + o_wa) + 1048576, 1179648);  // rows 512..1087
  cvt(wqb, wqbb, 1572864);
  cvt(wkvb, wkvbb, 2097152);
  cvt(wo, wob, 4194304);

  // merged down-projection: [q_lat | kv_lat | k_pe] = x @ [wq_a;wkv_a]^T
  gemm_bt<64><<<dim3(17, 32), 256, 0, stream>>>(xbf, wab, aproj, 4096, 1088, 2048);
  rmsnorm_bf16<<<4096, 256, 0, stream>>>(aproj, 1088, qnw, qlatn);
  rmsnorm_bf16<<<4096, 256, 0, stream>>>(aproj + 512, 1088, kvnw, kvlatn);
  rope_kpe<<<512, 256, 0, stream>>>(aproj, fc, kpe);

  // q = rmsnorm(q_lat) @ wq_b^T -> rope+scale+pack
  gemm_bt<128><<<dim3(24, 32), 256, 0, stream>>>(qlatn, wqbb, qfull, 4096, 3072, 512);
  rope_pack_q<<<24576, 256, 0, stream>>>(qfull, fc, qbf);

  // kv = rmsnorm(kv_lat) @ wkv_b^T -> pack k, transpose v
  gemm_bt<128><<<dim3(32, 32), 256, 0, stream>>>(kvlatn, wkvbb, kvb, 4096, 4096, 512);
  pack_k<<<24576, 256, 0, stream>>>(kvb, kpe, kbf);
  transpose_v<<<dim3(64, 4, 32), 256, 0, stream>>>(kvb, vt);

  // attention + output projection
  flash_attn<<<1024, 256, 0, stream>>>(qbf, kbf, vt, attnbf);
  gemm_bt<128><<<dim3(16, 32), 256, 0, stream>>>(attnbf, wob, out, 4096, 2048, 2048);
}

// Round 5
// 301.781 us; speedup vs baseline: 1.6093x; 1.0558x over previous
//
#include <hip/hip_runtime.h>
#include <cstdint>
#include <cstddef>

// ---------------------------------------------------------------------------
// MLA forward (B=2, S=2048, DIM=2048, H=16, Q_RANK=KV_RANK=512,
//              D_NOPE=128, D_ROPE=64, D_V=128, D_QK=192)
// Round 5: flash v5 — even/odd key interleave makes the PV B-fragment and the
//          softmax alpha/l state fully lane-local (zero cross-lane ops beyond
//          4 shfl_xor reduces); PV computes O^T = V^T P^T. Fused cvt kernel.
// ---------------------------------------------------------------------------

typedef unsigned short u16;
typedef unsigned int u32;
typedef unsigned long long u64;
typedef __attribute__((ext_vector_type(8))) short bf16x8;
typedef __attribute__((ext_vector_type(4))) float floatx4;

#define MFMA16x16x32 __builtin_amdgcn_mfma_f32_16x16x32_bf16

// Q is pre-scaled by SCALE * log2(e) so softmax runs in exp2 domain.
#define QSCALE 0.10411755f      // 192^-0.5 * 1.4426950408889634
#define THR_L2 11.541560f       // defer-max threshold 8.0 * log2(e)

__device__ __forceinline__ u16 f2bf(float f) {
  u32 u = __float_as_uint(f);
  u32 r = (u + 0x7fffu + ((u >> 16) & 1u)) >> 16;
  return (u16)r;
}

__device__ __forceinline__ void gload16(const void* g, void* l) {
  __builtin_amdgcn_global_load_lds(
      (const __attribute__((address_space(1))) void*)g,
      (__attribute__((address_space(3))) void*)l, 16, 0, 0);
}

// ---------------- fused f32 -> bf16 convert (6 segments, 1 dispatch) --------
__global__ __launch_bounds__(256) void cvt_all(
    const float* __restrict__ s0, const float* __restrict__ s1,
    const float* __restrict__ s2, const float* __restrict__ s3,
    const float* __restrict__ s4, const float* __restrict__ s5,
    u16* __restrict__ d0, u16* __restrict__ d1, u16* __restrict__ d2,
    u16* __restrict__ d3, u16* __restrict__ d4, u16* __restrict__ d5) {
  // segment sizes in float4 units (compile-time constants)
  constexpr int ST1 = 2097152;            // x        (8388608 el)
  constexpr int ST2 = ST1 + 262144;       // wq_a     (1048576 el)
  constexpr int ST3 = ST2 + 294912;       // wkv_a    (1179648 el)
  constexpr int ST4 = ST3 + 393216;       // wq_b     (1572864 el)
  constexpr int ST5 = ST4 + 524288;       // wkv_b    (2097152 el)
  constexpr int TOT = ST5 + 1048576;      // wo       (4194304 el)
  int i = blockIdx.x * 256 + threadIdx.x;
  int stride = gridDim.x * 256;
  for (; i < TOT; i += stride) {
    const float* sp;
    u16* dp;
    int j;
    if (i < ST1)      { sp = s0; dp = d0; j = i; }
    else if (i < ST2) { sp = s1; dp = d1; j = i - ST1; }
    else if (i < ST3) { sp = s2; dp = d2; j = i - ST2; }
    else if (i < ST4) { sp = s3; dp = d3; j = i - ST3; }
    else if (i < ST5) { sp = s4; dp = d4; j = i - ST4; }
    else              { sp = s5; dp = d5; j = i - ST5; }
    float4 v = ((const float4*)sp)[j];
    ushort4 o;
    o.x = f2bf(v.x); o.y = f2bf(v.y); o.z = f2bf(v.z); o.w = f2bf(v.w);
    ((ushort4*)dp)[j] = o;
  }
}

// ---------------- GEMM v2: C(M,N) f32 = A(M,K) bf16 @ B(N,K)^T bf16 ---------
// 128xBN tile, BK=32, 4 waves (2x2). Double-buffered LDS; per K-step:
// STAGE(next,buf^1) -> s_waitcnt vmcnt(L) -> s_barrier -> compute(buf) ->
// s_barrier. gload_lds staging with slot-XOR swizzle (pre-swizzled source).
template <int BN>
__global__ __launch_bounds__(256) void gemm_bt(const u16* __restrict__ A,
                                               const u16* __restrict__ B,
                                               float* __restrict__ C,
                                               int M, int N, int K) {
  constexpr int FN = BN / 32;
  constexpr int BL = BN / 64;
  __shared__ alignas(16) u16 As[2][128 * 32];
  __shared__ alignas(16) u16 Bs[2][BN * 32];
  const int m0 = blockIdx.y * 128, n0 = blockIdx.x * BN;
  const int t = threadIdx.x;
  const int wv = t >> 6, lane = t & 63, g = lane >> 4, qq = lane & 15;
  const int wr = wv >> 1, wc = wv & 1;
  const int fsw = (qq >> 1) & 3;  // read-side XOR == (row>>1)&3
  size_t aoff[2], boff[BL];
#pragma unroll
  for (int i = 0; i < 2; ++i) {
    int seg = t + i * 256;
    int row = seg >> 2, sl = seg & 3;
    aoff[i] = (size_t)(m0 + row) * K + (sl ^ ((row >> 1) & 3)) * 8;
  }
#pragma unroll
  for (int i = 0; i < BL; ++i) {
    int seg = t + i * 256;
    int row = seg >> 2, sl = seg & 3;
    boff[i] = (size_t)(n0 + row) * K + (sl ^ ((row >> 1) & 3)) * 8;
  }
  const floatx4 fz = {0.f, 0.f, 0.f, 0.f};
  floatx4 acc[4][FN];
#pragma unroll
  for (int m = 0; m < 4; ++m)
#pragma unroll
    for (int n = 0; n < FN; ++n) acc[m][n] = fz;

#define GSTAGE(buf, k0)                                                      \
  {                                                                          \
    _Pragma("unroll") for (int i = 0; i < 2; ++i)                            \
        gload16(&A[aoff[i] + (k0)], &As[buf][(size_t)(wv * 64 + i * 256) * 8]); \
    _Pragma("unroll") for (int i = 0; i < BL; ++i)                           \
        gload16(&B[boff[i] + (k0)], &Bs[buf][(size_t)(wv * 64 + i * 256) * 8]); \
  }

  const int nk = K >> 5;
  GSTAGE(0, 0);
  for (int kt = 0; kt < nk; ++kt) {
    asm volatile("" ::: "memory");
    if (kt + 1 < nk) {
      GSTAGE((kt + 1) & 1, (kt + 1) * 32);
      if constexpr (BN == 128)
        asm volatile("s_waitcnt vmcnt(4)" ::: "memory");
      else
        asm volatile("s_waitcnt vmcnt(3)" ::: "memory");
    } else {
      asm volatile("s_waitcnt vmcnt(0)" ::: "memory");
    }
    __builtin_amdgcn_s_barrier();
    asm volatile("" ::: "memory");
    const u16* Ab = &As[kt & 1][0];
    const u16* Bb = &Bs[kt & 1][0];
    bf16x8 af[4], bfr[FN];
#pragma unroll
    for (int m = 0; m < 4; ++m)
      af[m] = *(const bf16x8*)&Ab[(wr * 64 + m * 16 + qq) * 32 + ((g ^ fsw) * 8)];
#pragma unroll
    for (int n = 0; n < FN; ++n)
      bfr[n] = *(const bf16x8*)&Bb[(wc * (BN / 2) + n * 16 + qq) * 32 + ((g ^ fsw) * 8)];
    __builtin_amdgcn_s_setprio(1);
#pragma unroll
    for (int m = 0; m < 4; ++m)
#pragma unroll
      for (int n = 0; n < FN; ++n)
        acc[m][n] = MFMA16x16x32(af[m], bfr[n], acc[m][n], 0, 0, 0);
    __builtin_amdgcn_s_setprio(0);
    asm volatile("" ::: "memory");
    __builtin_amdgcn_s_barrier();
  }
#undef GSTAGE
#pragma unroll
  for (int m = 0; m < 4; ++m)
#pragma unroll
    for (int n = 0; n < FN; ++n)
#pragma unroll
      for (int r = 0; r < 4; ++r) {
        int row = m0 + wr * 64 + m * 16 + 4 * g + r;
        int col = n0 + wc * (BN / 2) + n * 16 + qq;
        C[(size_t)row * N + col] = acc[m][n][r];
      }
}

// ---------------- RMSNorm over 512 cols, f32 in -> bf16 out -----------------
__global__ __launch_bounds__(256) void rmsnorm_bf16(const float* __restrict__ in,
                                                    int stride,
                                                    const float* __restrict__ w,
                                                    u16* __restrict__ out) {
  const int row = blockIdx.x, t = threadIdx.x;
  __shared__ float wsum[4];
  float2 v = *(const float2*)&in[(size_t)row * stride + 2 * t];
  float ss = v.x * v.x + v.y * v.y;
#pragma unroll
  for (int off = 1; off < 64; off <<= 1) ss += __shfl_xor(ss, off);
  if ((t & 63) == 0) wsum[t >> 6] = ss;
  __syncthreads();
  float tot = wsum[0] + wsum[1] + wsum[2] + wsum[3];
  float r = rsqrtf(tot * (1.f / 512.f) + 1e-6f);
  out[(size_t)row * 512 + 2 * t] = f2bf(v.x * r * w[2 * t]);
  out[(size_t)row * 512 + 2 * t + 1] = f2bf(v.y * r * w[2 * t + 1]);
}

// ---------------- RoPE on k_pe (merged proj cols 1024..1087) -> bf16 --------
__global__ __launch_bounds__(256) void rope_kpe(const float* __restrict__ ap,
                                                const float* __restrict__ fc,
                                                u16* __restrict__ kpe) {
  int idx = blockIdx.x * 256 + threadIdx.x;  // 4096*32
  int row = idx >> 5, j = idx & 31;
  int s = row & 2047;
  float xr = ap[(size_t)row * 1088 + 1024 + 2 * j];
  float xi = ap[(size_t)row * 1088 + 1024 + 2 * j + 1];
  float c = fc[(s * 32 + j) * 2], sn = fc[(s * 32 + j) * 2 + 1];
  u32 lo = f2bf(xr * c - xi * sn), hi = f2bf(xr * sn + xi * c);
  *(u32*)&kpe[(size_t)row * 64 + 2 * j] = lo | (hi << 16);
}

// ---------------- RoPE + scale + pack q: -> [bh][s][192] bf16 ---------------
__global__ __launch_bounds__(256) void rope_pack_q(const float* __restrict__ qf,
                                                   const float* __restrict__ fc,
                                                   u16* __restrict__ qbf) {
  int idx = blockIdx.x * 256 + threadIdx.x;  // 4096*16*96
  int j = idx % 96;
  int rh = idx / 96;
  int h = rh & 15, row = rh >> 4;
  int b = row >> 11, s = row & 2047;
  const float* src = qf + (size_t)row * 3072 + h * 192;
  u16* dst = qbf + ((size_t)(b * 16 + h) * 2048 + s) * 192;
  if (j < 64) {
    u32 lo = f2bf(src[2 * j] * QSCALE), hi = f2bf(src[2 * j + 1] * QSCALE);
    *(u32*)&dst[2 * j] = lo | (hi << 16);
  } else {
    int jp = j - 64;
    float xr = src[128 + 2 * jp], xi = src[128 + 2 * jp + 1];
    float c = fc[(s * 32 + jp) * 2], sn = fc[(s * 32 + jp) * 2 + 1];
    u32 lo = f2bf((xr * c - xi * sn) * QSCALE);
    u32 hi = f2bf((xr * sn + xi * c) * QSCALE);
    *(u32*)&dst[128 + 2 * jp] = lo | (hi << 16);
  }
}

// ---------------- pack k: kv_b nope + broadcast k_pe -> [bh][s][192] --------
__global__ __launch_bounds__(256) void pack_k(const float* __restrict__ kvb,
                                              const u16* __restrict__ kpe,
                                              u16* __restrict__ kbf) {
  int idx = blockIdx.x * 256 + threadIdx.x;  // 4096*16*96
  int j = idx % 96;
  int rh = idx / 96;
  int h = rh & 15, row = rh >> 4;
  int b = row >> 11, s = row & 2047;
  u16* dst = kbf + ((size_t)(b * 16 + h) * 2048 + s) * 192;
  if (j < 64) {
    const float* src = kvb + (size_t)row * 4096 + h * 256;
    u32 lo = f2bf(src[2 * j]), hi = f2bf(src[2 * j + 1]);
    *(u32*)&dst[2 * j] = lo | (hi << 16);
  } else {
    int jp = j - 64;
    *(u32*)&dst[128 + 2 * jp] = *(const u32*)&kpe[(size_t)row * 64 + 2 * jp];
  }
}

// ---------------- transpose v: kv_b[...,128:256] -> vt [bh][dv=128][s] ------
__global__ __launch_bounds__(256) void transpose_v(const float* __restrict__ kvb,
                                                   u16* __restrict__ vt) {
  __shared__ u16 T[32][34];
  const int bh = blockIdx.z, b = bh >> 4, h = bh & 15;
  const int s0 = blockIdx.x * 32, d0 = blockIdx.y * 32;
  const int tx = threadIdx.x & 31, ty = threadIdx.x >> 5;
#pragma unroll
  for (int i = 0; i < 4; ++i) {
    int sl = ty + i * 8;
    float v = kvb[(size_t)(b * 2048 + s0 + sl) * 4096 + h * 256 + 128 + d0 + tx];
    T[sl][tx] = f2bf(v);
  }
  __syncthreads();
#pragma unroll
  for (int i = 0; i < 4; ++i) {
    int dl = ty + i * 8;
    vt[((size_t)bh * 128 + d0 + dl) * 2048 + s0 + tx] = T[tx][dl];
  }
}

// ---------------- flash attention v5 ----------------------------------------
// grid 1024 = (qt 32 x bh 32) longest-first; 4 waves x 16 q-rows (QBLK=64);
// KV=32/tile double-buffered, counted vmcnt(5).
// Even/odd key interleave: QK^T tile0 A-row qq <- key 2qq (even keys),
// tile1 <- key 2qq+1 (odd). Lane (qq,g) then holds P for keys {8g..8g+7} of
// q=qq -> PV B-fragment is LANE-LOCAL (interleave pex0/pex1). PV computes
// O^T = V^T * P^T, so cols = q = qq: alpha-rescale and 1/l also lane-local.
// Only cross-lane ops left: 4 shfl_xor (max+sum reduces).
__global__ __launch_bounds__(256, 4) void flash_attn(const u16* __restrict__ Q,
                                                     const u16* __restrict__ Kc,
                                                     const u16* __restrict__ VT,
                                                     u16* __restrict__ O) {
  __shared__ alignas(16) u16 Ks[2][32 * 192];  // 12 KB each
  __shared__ alignas(16) u16 Vs[2][128 * 32];  // 8 KB each
  const int bid = blockIdx.x;
  const int qt = 31 - (bid >> 5);  // longest blocks first
  const int bh = bid & 31;
  const int t = threadIdx.x, wv = t >> 6, lane = t & 63;
  const int g = lane >> 4, qq = lane & 15;
  const int qrow0 = qt * 64 + wv * 16;
  const int my_last = qrow0 + 15;
  const int q_glob = qrow0 + qq;
  const int nkt = 2 * qt + 2;

  // per-thread staging offsets (u16 units), iteration-invariant
  int koffg[3], voffg[2];
#pragma unroll
  for (int i = 0; i < 3; ++i) {
    int seg = t + i * 256;
    int row = seg / 24, sl = seg - row * 24;
    koffg[i] = row * 192 + (sl ^ (row & 7)) * 8;
  }
#pragma unroll
  for (int i = 0; i < 2; ++i) {
    int seg = t + i * 256;
    int row = seg >> 2, sl = seg & 3;
    voffg[i] = row * 2048 + (sl ^ ((row >> 1) & 3)) * 8;
  }
  const u16* Kt0 = Kc + (size_t)bh * 2048 * 192;
  const u16* Vt0 = VT + (size_t)bh * 128 * 2048;

  bf16x8 qf[6];
  {
    const u16* qp = Q + ((size_t)bh * 2048 + qrow0 + qq) * 192;
#pragma unroll
    for (int kk = 0; kk < 6; ++kk) qf[kk] = *(const bf16x8*)&qp[kk * 32 + g * 8];
  }
  asm volatile("s_waitcnt vmcnt(0)" ::: "memory");  // drain Q before pipeline

  const floatx4 fz = {0.f, 0.f, 0.f, 0.f};
  floatx4 oacc[8];
#pragma unroll
  for (int d = 0; d < 8; ++d) oacc[d] = fz;
  float m_run = -1e30f, l_run = 0.f;

  // K-row read indices for even/odd interleave
  const int krow0 = 2 * qq;            // even-key A rows
  const int krow1 = 2 * qq + 1;        // odd-key A rows
  const int xr0 = krow0 & 7, xr1 = krow1 & 7;
  const int vsw = (qq >> 1) & 3;       // V read-side slot XOR

#define STAGE(buf, kt)                                                       \
  {                                                                          \
    const u16* Kg = Kt0 + (size_t)(kt) * (32 * 192);                         \
    const u16* Vg = Vt0 + (kt) * 32;                                         \
    _Pragma("unroll") for (int i = 0; i < 3; ++i)                            \
        gload16(Kg + koffg[i], &Ks[buf][(size_t)(wv * 64 + i * 256) * 8]);   \
    _Pragma("unroll") for (int i = 0; i < 2; ++i)                            \
        gload16(Vg + voffg[i], &Vs[buf][(size_t)(wv * 64 + i * 256) * 8]);   \
  }

  STAGE(0, 0);
  for (int kt = 0; kt < nkt; ++kt) {
    const int k0 = kt * 32;
    asm volatile("" ::: "memory");
    if (kt + 1 < nkt) {
      STAGE((kt + 1) & 1, kt + 1);
      asm volatile("s_waitcnt vmcnt(5)" ::: "memory");
    } else {
      asm volatile("s_waitcnt vmcnt(0)" ::: "memory");
    }
    __builtin_amdgcn_s_barrier();
    asm volatile("" ::: "memory");
    if (k0 <= my_last) {  // wave-uniform
      const u16* Kb = &Ks[kt & 1][0];
      const u16* Vb = &Vs[kt & 1][0];
      floatx4 s0 = fz, s1 = fz;  // s0: even keys 2*(4g+r); s1: odd +1
      __builtin_amdgcn_s_setprio(1);
#pragma unroll
      for (int kk = 0; kk < 6; ++kk) {
        int sl = kk * 4 + g;
        bf16x8 a0 = *(const bf16x8*)&Kb[krow0 * 192 + ((sl ^ xr0) * 8)];
        bf16x8 a1 = *(const bf16x8*)&Kb[krow1 * 192 + ((sl ^ xr1) * 8)];
        s0 = MFMA16x16x32(a0, qf[kk], s0, 0, 0, 0);
        s1 = MFMA16x16x32(a1, qf[kk], s1, 0, 0, 0);
      }
      __builtin_amdgcn_s_setprio(0);
      float v[8];  // v[r]: key k0+8g+2r ; v[4+r]: key k0+8g+2r+1
      if (k0 + 31 <= qrow0) {  // fully-unmasked fast path (wave-uniform)
#pragma unroll
        for (int r = 0; r < 4; ++r) {
          v[r] = s0[r];
          v[4 + r] = s1[r];
        }
      } else {
#pragma unroll
        for (int r = 0; r < 4; ++r) {
          int key0 = k0 + 8 * g + 2 * r;
          v[r] = (key0 <= q_glob) ? s0[r] : -1e30f;
          v[4 + r] = (key0 + 1 <= q_glob) ? s1[r] : -1e30f;
        }
      }
      float mx = fmaxf(fmaxf(fmaxf(v[0], v[1]), fmaxf(v[2], v[3])),
                       fmaxf(fmaxf(v[4], v[5]), fmaxf(v[6], v[7])));
      mx = fmaxf(mx, __shfl_xor(mx, 16));
      mx = fmaxf(mx, __shfl_xor(mx, 32));  // row-max for q=qq
      if (!__all(mx <= m_run + THR_L2)) {  // defer-max (T13)
        float m_new = fmaxf(m_run, mx);
        float alpha = exp2f(m_run - m_new);
        m_run = m_new;
        l_run *= alpha;
#pragma unroll
        for (int d = 0; d < 8; ++d)
#pragma unroll
          for (int r = 0; r < 4; ++r) oacc[d][r] *= alpha;  // lane-local
      }
      float pex[8], sum = 0.f;
#pragma unroll
      for (int i = 0; i < 8; ++i) {
        pex[i] = exp2f(v[i] - m_run);
        sum += pex[i];
      }
      sum += __shfl_xor(sum, 16);
      sum += __shfl_xor(sum, 32);
      l_run += sum;
      // PV B-fragment: keys 8g..8g+7 = interleave(even pex[0..3], odd pex[4..7])
      bf16x8 pf;
      ((u32*)&pf)[0] = (u32)f2bf(pex[0]) | ((u32)f2bf(pex[4]) << 16);
      ((u32*)&pf)[1] = (u32)f2bf(pex[1]) | ((u32)f2bf(pex[5]) << 16);
      ((u32*)&pf)[2] = (u32)f2bf(pex[2]) | ((u32)f2bf(pex[6]) << 16);
      ((u32*)&pf)[3] = (u32)f2bf(pex[3]) | ((u32)f2bf(pex[7]) << 16);
      __builtin_amdgcn_s_setprio(1);
#pragma unroll
      for (int d = 0; d < 8; ++d) {
        // A = V^T fragment: row = dtile*16+qq, k = 8g..8g+7
        bf16x8 vf = *(const bf16x8*)&Vb[(d * 16 + qq) * 32 + ((g ^ vsw) * 8)];
        oacc[d] = MFMA16x16x32(vf, pf, oacc[d], 0, 0, 0);  // O^T: rows=d, cols=q
      }
      __builtin_amdgcn_s_setprio(0);
    }
    asm volatile("" ::: "memory");
    __builtin_amdgcn_s_barrier();
  }
#undef STAGE
  // epilogue: lane-local 1/l; lane owns q-row (qrow0+qq), d = dtile*16+4g+r
  float linv = 1.f / l_run;
  const int b = bh >> 4, h = bh & 15;
  size_t rowoff = ((size_t)b * 2048 + qrow0 + qq) * 2048 + h * 128 + 4 * g;
#pragma unroll
  for (int d = 0; d < 8; ++d) {
    u32 lo = (u32)f2bf(oacc[d][0] * linv) | ((u32)f2bf(oacc[d][1] * linv) << 16);
    u32 hi = (u32)f2bf(oacc[d][2] * linv) | ((u32)f2bf(oacc[d][3] * linv) << 16);
    u64 w = (u64)lo | ((u64)hi << 32);
    *(u64*)&O[rowoff + d * 16] = w;
  }
}

// ---------------------------------------------------------------------------
extern "C" void kernel_launch(void* const* d_in, const int* in_sizes, int n_in,
                              void* d_out, int out_size, void* d_ws,
                              size_t ws_size, hipStream_t stream) {
  (void)in_sizes; (void)n_in; (void)out_size;
  const float* x = (const float*)d_in[0];
  const float* fc = (const float*)d_in[1];
  const float* wqa = (const float*)d_in[2];
  const float* wqb = (const float*)d_in[3];
  const float* qnw = (const float*)d_in[4];
  const float* wkva = (const float*)d_in[5];
  const float* kvnw = (const float*)d_in[6];
  const float* wkvb = (const float*)d_in[7];
  const float* wo = (const float*)d_in[8];
  float* out = (float*)d_out;
  char* ws = (char*)d_ws;

  size_t off = 0;
  auto alloc = [&](size_t bytes) {
    size_t o = off;
    off += (bytes + 255) & ~(size_t)255;
    return o;
  };
  const size_t o_xbf = alloc(16777216);   // x bf16; later aliased by attn_out
  const size_t o_wa = alloc(4456448);     // merged [wq_a;wkv_a] bf16 (1088x2048)
  const size_t o_wqb = alloc(3145728);
  const size_t o_wkvb = alloc(4194304);
  const size_t o_wo = alloc(8388608);
  const size_t o_qln = alloc(4194304);    // q_lat normed bf16
  const size_t o_kvln = alloc(4194304);   // kv_lat normed bf16
  const size_t o_kpe = alloc(524288);     // roped k_pe bf16
  const size_t o_big = alloc(67108864);   // f32: aproj -> qfull -> kvb
  const size_t o_qbf = alloc(25165824);   // q packed [bh][s][192] (pre-scaled)
  const size_t o_kbf = alloc(25165824);   // k packed [bh][s][192]
  const size_t o_vt = alloc(16777216);    // v^T [bh][128][2048]
  if (ws_size < off) return;

  u16* xbf = (u16*)(ws + o_xbf);
  u16* wab = (u16*)(ws + o_wa);           // rows 0..511 wq_a, 512..1087 wkv_a
  u16* wqbb = (u16*)(ws + o_wqb);
  u16* wkvbb = (u16*)(ws + o_wkvb);
  u16* wob = (u16*)(ws + o_wo);
  u16* qlatn = (u16*)(ws + o_qln);
  u16* kvlatn = (u16*)(ws + o_kvln);
  u16* kpe = (u16*)(ws + o_kpe);
  float* aproj = (float*)(ws + o_big);    // 4096x1088 f32
  float* qfull = (float*)(ws + o_big);    // 4096x3072 f32 (after aproj dead)
  float* kvb = (float*)(ws + o_big);      // 4096x4096 f32 (after qfull dead)
  u16* qbf = (u16*)(ws + o_qbf);
  u16* kbf = (u16*)(ws + o_kbf);
  u16* vt = (u16*)(ws + o_vt);
  u16* attnbf = (u16*)(ws + o_xbf);       // aliases xbf (dead after aproj)

  // one fused cvt dispatch for x + 5 weights
  cvt_all<<<2048, 256, 0, stream>>>(x, wqa, wkva, wqb, wkvb, wo,
                                    xbf, wab, wab + 1048576, wqbb, wkvbb, wob);

  // merged down-projection: [q_lat | kv_lat | k_pe] = x @ [wq_a;wkv_a]^T
  gemm_bt<64><<<dim3(17, 32), 256, 0, stream>>>(xbf, wab, aproj, 4096, 1088, 2048);
  rmsnorm_bf16<<<4096, 256, 0, stream>>>(aproj, 1088, qnw, qlatn);
  rmsnorm_bf16<<<4096, 256, 0, stream>>>(aproj + 512, 1088, kvnw, kvlatn);
  rope_kpe<<<512, 256, 0, stream>>>(aproj, fc, kpe);

  // q = rmsnorm(q_lat) @ wq_b^T -> rope+scale+pack
  gemm_bt<128><<<dim3(24, 32), 256, 0, stream>>>(qlatn, wqbb, qfull, 4096, 3072, 512);
  rope_pack_q<<<24576, 256, 0, stream>>>(qfull, fc, qbf);

  // kv = rmsnorm(kv_lat) @ wkv_b^T -> pack k, transpose v
  gemm_bt<128><<<dim3(32, 32), 256, 0, stream>>>(kvlatn, wkvbb, kvb, 4096, 4096, 512);
  pack_k<<<24576, 256, 0, stream>>>(kvb, kpe, kbf);
  transpose_v<<<dim3(64, 4, 32), 256, 0, stream>>>(kvb, vt);

  // attention + output projection
  flash_attn<<<1024, 256, 0, stream>>>(qbf, kbf, vt, attnbf);
  gemm_bt<128><<<dim3(16, 32), 256, 0, stream>>>(attnbf, wob, out, 4096, 2048, 2048);
}

// Round 6
// 289.314 us; speedup vs baseline: 1.6786x; 1.0431x over previous
//
#include <hip/hip_runtime.h>
#include <cstdint>
#include <cstddef>

// ---------------------------------------------------------------------------
// MLA forward (B=2, S=2048, DIM=2048, H=16, Q_RANK=KV_RANK=512,
//              D_NOPE=128, D_ROPE=64, D_V=128, D_QK=192)
// Round 6: flash v6 — K-swizzle fixed to (row>>1)&7 (2-way, free); softmax
//          sum via ones-MFMA into oacc_l (no sum tree/shfl); shfl-free
//          defer-max fast path; v_cvt_pk_bf16_f32 P pack.
// ---------------------------------------------------------------------------

typedef unsigned short u16;
typedef unsigned int u32;
typedef unsigned long long u64;
typedef __attribute__((ext_vector_type(8))) short bf16x8;
typedef __attribute__((ext_vector_type(4))) float floatx4;

#define MFMA16x16x32 __builtin_amdgcn_mfma_f32_16x16x32_bf16

// Q is pre-scaled by SCALE * log2(e) so softmax runs in exp2 domain.
#define QSCALE 0.10411755f      // 192^-0.5 * 1.4426950408889634
#define THR_L2 11.541560f       // defer-max threshold 8.0 * log2(e)

__device__ __forceinline__ u16 f2bf(float f) {
  u32 u = __float_as_uint(f);
  u32 r = (u + 0x7fffu + ((u >> 16) & 1u)) >> 16;
  return (u16)r;
}

__device__ __forceinline__ u32 cvtpk(float lo, float hi) {
  u32 r;
  asm("v_cvt_pk_bf16_f32 %0, %1, %2" : "=v"(r) : "v"(lo), "v"(hi));
  return r;
}

__device__ __forceinline__ void gload16(const void* g, void* l) {
  __builtin_amdgcn_global_load_lds(
      (const __attribute__((address_space(1))) void*)g,
      (__attribute__((address_space(3))) void*)l, 16, 0, 0);
}

// ---------------- fused f32 -> bf16 convert (6 segments, 1 dispatch) --------
__global__ __launch_bounds__(256) void cvt_all(
    const float* __restrict__ s0, const float* __restrict__ s1,
    const float* __restrict__ s2, const float* __restrict__ s3,
    const float* __restrict__ s4, const float* __restrict__ s5,
    u16* __restrict__ d0, u16* __restrict__ d1, u16* __restrict__ d2,
    u16* __restrict__ d3, u16* __restrict__ d4, u16* __restrict__ d5) {
  constexpr int ST1 = 2097152;            // x        (8388608 el)
  constexpr int ST2 = ST1 + 262144;       // wq_a     (1048576 el)
  constexpr int ST3 = ST2 + 294912;       // wkv_a    (1179648 el)
  constexpr int ST4 = ST3 + 393216;       // wq_b     (1572864 el)
  constexpr int ST5 = ST4 + 524288;       // wkv_b    (2097152 el)
  constexpr int TOT = ST5 + 1048576;      // wo       (4194304 el)
  int i = blockIdx.x * 256 + threadIdx.x;
  int stride = gridDim.x * 256;
  for (; i < TOT; i += stride) {
    const float* sp;
    u16* dp;
    int j;
    if (i < ST1)      { sp = s0; dp = d0; j = i; }
    else if (i < ST2) { sp = s1; dp = d1; j = i - ST1; }
    else if (i < ST3) { sp = s2; dp = d2; j = i - ST2; }
    else if (i < ST4) { sp = s3; dp = d3; j = i - ST3; }
    else if (i < ST5) { sp = s4; dp = d4; j = i - ST4; }
    else              { sp = s5; dp = d5; j = i - ST5; }
    float4 v = ((const float4*)sp)[j];
    ushort4 o;
    o.x = f2bf(v.x); o.y = f2bf(v.y); o.z = f2bf(v.z); o.w = f2bf(v.w);
    ((ushort4*)dp)[j] = o;
  }
}

// ---------------- GEMM v2: C(M,N) f32 = A(M,K) bf16 @ B(N,K)^T bf16 ---------
template <int BN>
__global__ __launch_bounds__(256) void gemm_bt(const u16* __restrict__ A,
                                               const u16* __restrict__ B,
                                               float* __restrict__ C,
                                               int M, int N, int K) {
  constexpr int FN = BN / 32;
  constexpr int BL = BN / 64;
  __shared__ alignas(16) u16 As[2][128 * 32];
  __shared__ alignas(16) u16 Bs[2][BN * 32];
  const int m0 = blockIdx.y * 128, n0 = blockIdx.x * BN;
  const int t = threadIdx.x;
  const int wv = t >> 6, lane = t & 63, g = lane >> 4, qq = lane & 15;
  const int wr = wv >> 1, wc = wv & 1;
  const int fsw = (qq >> 1) & 3;  // read-side XOR == (row>>1)&3
  size_t aoff[2], boff[BL];
#pragma unroll
  for (int i = 0; i < 2; ++i) {
    int seg = t + i * 256;
    int row = seg >> 2, sl = seg & 3;
    aoff[i] = (size_t)(m0 + row) * K + (sl ^ ((row >> 1) & 3)) * 8;
  }
#pragma unroll
  for (int i = 0; i < BL; ++i) {
    int seg = t + i * 256;
    int row = seg >> 2, sl = seg & 3;
    boff[i] = (size_t)(n0 + row) * K + (sl ^ ((row >> 1) & 3)) * 8;
  }
  const floatx4 fz = {0.f, 0.f, 0.f, 0.f};
  floatx4 acc[4][FN];
#pragma unroll
  for (int m = 0; m < 4; ++m)
#pragma unroll
    for (int n = 0; n < FN; ++n) acc[m][n] = fz;

#define GSTAGE(buf, k0)                                                      \
  {                                                                          \
    _Pragma("unroll") for (int i = 0; i < 2; ++i)                            \
        gload16(&A[aoff[i] + (k0)], &As[buf][(size_t)(wv * 64 + i * 256) * 8]); \
    _Pragma("unroll") for (int i = 0; i < BL; ++i)                           \
        gload16(&B[boff[i] + (k0)], &Bs[buf][(size_t)(wv * 64 + i * 256) * 8]); \
  }

  const int nk = K >> 5;
  GSTAGE(0, 0);
  for (int kt = 0; kt < nk; ++kt) {
    asm volatile("" ::: "memory");
    if (kt + 1 < nk) {
      GSTAGE((kt + 1) & 1, (kt + 1) * 32);
      if constexpr (BN == 128)
        asm volatile("s_waitcnt vmcnt(4)" ::: "memory");
      else
        asm volatile("s_waitcnt vmcnt(3)" ::: "memory");
    } else {
      asm volatile("s_waitcnt vmcnt(0)" ::: "memory");
    }
    __builtin_amdgcn_s_barrier();
    asm volatile("" ::: "memory");
    const u16* Ab = &As[kt & 1][0];
    const u16* Bb = &Bs[kt & 1][0];
    bf16x8 af[4], bfr[FN];
#pragma unroll
    for (int m = 0; m < 4; ++m)
      af[m] = *(const bf16x8*)&Ab[(wr * 64 + m * 16 + qq) * 32 + ((g ^ fsw) * 8)];
#pragma unroll
    for (int n = 0; n < FN; ++n)
      bfr[n] = *(const bf16x8*)&Bb[(wc * (BN / 2) + n * 16 + qq) * 32 + ((g ^ fsw) * 8)];
    __builtin_amdgcn_s_setprio(1);
#pragma unroll
    for (int m = 0; m < 4; ++m)
#pragma unroll
      for (int n = 0; n < FN; ++n)
        acc[m][n] = MFMA16x16x32(af[m], bfr[n], acc[m][n], 0, 0, 0);
    __builtin_amdgcn_s_setprio(0);
    asm volatile("" ::: "memory");
    __builtin_amdgcn_s_barrier();
  }
#undef GSTAGE
#pragma unroll
  for (int m = 0; m < 4; ++m)
#pragma unroll
    for (int n = 0; n < FN; ++n)
#pragma unroll
      for (int r = 0; r < 4; ++r) {
        int row = m0 + wr * 64 + m * 16 + 4 * g + r;
        int col = n0 + wc * (BN / 2) + n * 16 + qq;
        C[(size_t)row * N + col] = acc[m][n][r];
      }
}

// ---------------- RMSNorm over 512 cols, f32 in -> bf16 out -----------------
__global__ __launch_bounds__(256) void rmsnorm_bf16(const float* __restrict__ in,
                                                    int stride,
                                                    const float* __restrict__ w,
                                                    u16* __restrict__ out) {
  const int row = blockIdx.x, t = threadIdx.x;
  __shared__ float wsum[4];
  float2 v = *(const float2*)&in[(size_t)row * stride + 2 * t];
  float ss = v.x * v.x + v.y * v.y;
#pragma unroll
  for (int off = 1; off < 64; off <<= 1) ss += __shfl_xor(ss, off);
  if ((t & 63) == 0) wsum[t >> 6] = ss;
  __syncthreads();
  float tot = wsum[0] + wsum[1] + wsum[2] + wsum[3];
  float r = rsqrtf(tot * (1.f / 512.f) + 1e-6f);
  out[(size_t)row * 512 + 2 * t] = f2bf(v.x * r * w[2 * t]);
  out[(size_t)row * 512 + 2 * t + 1] = f2bf(v.y * r * w[2 * t + 1]);
}

// ---------------- RoPE on k_pe (merged proj cols 1024..1087) -> bf16 --------
__global__ __launch_bounds__(256) void rope_kpe(const float* __restrict__ ap,
                                                const float* __restrict__ fc,
                                                u16* __restrict__ kpe) {
  int idx = blockIdx.x * 256 + threadIdx.x;  // 4096*32
  int row = idx >> 5, j = idx & 31;
  int s = row & 2047;
  float xr = ap[(size_t)row * 1088 + 1024 + 2 * j];
  float xi = ap[(size_t)row * 1088 + 1024 + 2 * j + 1];
  float c = fc[(s * 32 + j) * 2], sn = fc[(s * 32 + j) * 2 + 1];
  u32 lo = f2bf(xr * c - xi * sn), hi = f2bf(xr * sn + xi * c);
  *(u32*)&kpe[(size_t)row * 64 + 2 * j] = lo | (hi << 16);
}

// ---------------- RoPE + scale + pack q: -> [bh][s][192] bf16 ---------------
__global__ __launch_bounds__(256) void rope_pack_q(const float* __restrict__ qf,
                                                   const float* __restrict__ fc,
                                                   u16* __restrict__ qbf) {
  int idx = blockIdx.x * 256 + threadIdx.x;  // 4096*16*96
  int j = idx % 96;
  int rh = idx / 96;
  int h = rh & 15, row = rh >> 4;
  int b = row >> 11, s = row & 2047;
  const float* src = qf + (size_t)row * 3072 + h * 192;
  u16* dst = qbf + ((size_t)(b * 16 + h) * 2048 + s) * 192;
  if (j < 64) {
    u32 lo = f2bf(src[2 * j] * QSCALE), hi = f2bf(src[2 * j + 1] * QSCALE);
    *(u32*)&dst[2 * j] = lo | (hi << 16);
  } else {
    int jp = j - 64;
    float xr = src[128 + 2 * jp], xi = src[128 + 2 * jp + 1];
    float c = fc[(s * 32 + jp) * 2], sn = fc[(s * 32 + jp) * 2 + 1];
    u32 lo = f2bf((xr * c - xi * sn) * QSCALE);
    u32 hi = f2bf((xr * sn + xi * c) * QSCALE);
    *(u32*)&dst[128 + 2 * jp] = lo | (hi << 16);
  }
}

// ---------------- pack k: kv_b nope + broadcast k_pe -> [bh][s][192] --------
__global__ __launch_bounds__(256) void pack_k(const float* __restrict__ kvb,
                                              const u16* __restrict__ kpe,
                                              u16* __restrict__ kbf) {
  int idx = blockIdx.x * 256 + threadIdx.x;  // 4096*16*96
  int j = idx % 96;
  int rh = idx / 96;
  int h = rh & 15, row = rh >> 4;
  int b = row >> 11, s = row & 2047;
  u16* dst = kbf + ((size_t)(b * 16 + h) * 2048 + s) * 192;
  if (j < 64) {
    const float* src = kvb + (size_t)row * 4096 + h * 256;
    u32 lo = f2bf(src[2 * j]), hi = f2bf(src[2 * j + 1]);
    *(u32*)&dst[2 * j] = lo | (hi << 16);
  } else {
    int jp = j - 64;
    *(u32*)&dst[128 + 2 * jp] = *(const u32*)&kpe[(size_t)row * 64 + 2 * jp];
  }
}

// ---------------- transpose v: kv_b[...,128:256] -> vt [bh][dv=128][s] ------
__global__ __launch_bounds__(256) void transpose_v(const float* __restrict__ kvb,
                                                   u16* __restrict__ vt) {
  __shared__ u16 T[32][34];
  const int bh = blockIdx.z, b = bh >> 4, h = bh & 15;
  const int s0 = blockIdx.x * 32, d0 = blockIdx.y * 32;
  const int tx = threadIdx.x & 31, ty = threadIdx.x >> 5;
#pragma unroll
  for (int i = 0; i < 4; ++i) {
    int sl = ty + i * 8;
    float v = kvb[(size_t)(b * 2048 + s0 + sl) * 4096 + h * 256 + 128 + d0 + tx];
    T[sl][tx] = f2bf(v);
  }
  __syncthreads();
#pragma unroll
  for (int i = 0; i < 4; ++i) {
    int dl = ty + i * 8;
    vt[((size_t)bh * 128 + d0 + dl) * 2048 + s0 + tx] = T[tx][dl];
  }
}

// ---------------- flash attention v6 ----------------------------------------
// grid 1024 = (qt 32 x bh 32) longest-first; 4 waves x 16 q-rows (QBLK=64);
// KV=32/tile double-buffered, counted vmcnt(5). Even/odd key interleave ->
// lane-local PV B-frag + lane-local softmax state. l via ones-MFMA (oacc_l).
// Shfl-free defer-max fast path. cvt_pk P pack.
__global__ __launch_bounds__(256, 4) void flash_attn(const u16* __restrict__ Q,
                                                     const u16* __restrict__ Kc,
                                                     const u16* __restrict__ VT,
                                                     u16* __restrict__ O) {
  __shared__ alignas(16) u16 Ks[2][32 * 192];  // 12 KB each
  __shared__ alignas(16) u16 Vs[2][128 * 32];  // 8 KB each
  const int bid = blockIdx.x;
  const int qt = 31 - (bid >> 5);  // longest blocks first
  const int bh = bid & 31;
  const int t = threadIdx.x, wv = t >> 6, lane = t & 63;
  const int g = lane >> 4, qq = lane & 15;
  const int qrow0 = qt * 64 + wv * 16;
  const int my_last = qrow0 + 15;
  const int q_glob = qrow0 + qq;
  const int nkt = 2 * qt + 2;

  // per-thread staging offsets (u16 units), iteration-invariant
  int koffg[3], voffg[2];
#pragma unroll
  for (int i = 0; i < 3; ++i) {
    int seg = t + i * 256;
    int row = seg / 24, sl = seg - row * 24;
    koffg[i] = row * 192 + (sl ^ ((row >> 1) & 7)) * 8;  // class (row>>1)&7
  }
#pragma unroll
  for (int i = 0; i < 2; ++i) {
    int seg = t + i * 256;
    int row = seg >> 2, sl = seg & 3;
    voffg[i] = row * 2048 + (sl ^ ((row >> 1) & 3)) * 8;
  }
  const u16* Kt0 = Kc + (size_t)bh * 2048 * 192;
  const u16* Vt0 = VT + (size_t)bh * 128 * 2048;

  bf16x8 qf[6];
  {
    const u16* qp = Q + ((size_t)bh * 2048 + qrow0 + qq) * 192;
#pragma unroll
    for (int kk = 0; kk < 6; ++kk) qf[kk] = *(const bf16x8*)&qp[kk * 32 + g * 8];
  }
  asm volatile("s_waitcnt vmcnt(0)" ::: "memory");  // drain Q before pipeline

  const floatx4 fz = {0.f, 0.f, 0.f, 0.f};
  floatx4 oacc[8];
  floatx4 oacc_l = fz;  // ones-MFMA softmax-denominator accumulator
#pragma unroll
  for (int d = 0; d < 8; ++d) oacc[d] = fz;
  float m_run = -1e30f;

  // ones A-fragment for the l-accumulator MFMA
  bf16x8 ones;
#pragma unroll
  for (int i = 0; i < 8; ++i) ones[i] = (short)0x3f80;  // bf16 1.0

  // K-row read indices (even/odd interleave); swizzle class (row>>1)&7 == qq&7
  const int krow0 = 2 * qq;
  const int krow1 = 2 * qq + 1;
  const int xrk = qq & 7;
  const int vsw = (qq >> 1) & 3;  // V read-side slot XOR

#define STAGE(buf, kt)                                                       \
  {                                                                          \
    const u16* Kg = Kt0 + (size_t)(kt) * (32 * 192);                         \
    const u16* Vg = Vt0 + (kt) * 32;                                         \
    _Pragma("unroll") for (int i = 0; i < 3; ++i)                            \
        gload16(Kg + koffg[i], &Ks[buf][(size_t)(wv * 64 + i * 256) * 8]);   \
    _Pragma("unroll") for (int i = 0; i < 2; ++i)                            \
        gload16(Vg + voffg[i], &Vs[buf][(size_t)(wv * 64 + i * 256) * 8]);   \
  }

  STAGE(0, 0);
  for (int kt = 0; kt < nkt; ++kt) {
    const int k0 = kt * 32;
    asm volatile("" ::: "memory");
    if (kt + 1 < nkt) {
      STAGE((kt + 1) & 1, kt + 1);
      asm volatile("s_waitcnt vmcnt(5)" ::: "memory");
    } else {
      asm volatile("s_waitcnt vmcnt(0)" ::: "memory");
    }
    __builtin_amdgcn_s_barrier();
    asm volatile("" ::: "memory");
    if (k0 <= my_last) {  // wave-uniform
      const u16* Kb = &Ks[kt & 1][0];
      const u16* Vb = &Vs[kt & 1][0];
      floatx4 s0 = fz, s1 = fz;  // s0: even keys 8g+2r; s1: odd 8g+2r+1
      __builtin_amdgcn_s_setprio(1);
#pragma unroll
      for (int kk = 0; kk < 6; ++kk) {
        int sl = kk * 4 + g;
        bf16x8 a0 = *(const bf16x8*)&Kb[krow0 * 192 + ((sl ^ xrk) * 8)];
        bf16x8 a1 = *(const bf16x8*)&Kb[krow1 * 192 + ((sl ^ xrk) * 8)];
        s0 = MFMA16x16x32(a0, qf[kk], s0, 0, 0, 0);
        s1 = MFMA16x16x32(a1, qf[kk], s1, 0, 0, 0);
      }
      __builtin_amdgcn_s_setprio(0);
      float v[8];  // v[r]: key k0+8g+2r ; v[4+r]: key k0+8g+2r+1
      if (k0 + 31 <= qrow0) {  // fully-unmasked fast path (wave-uniform)
#pragma unroll
        for (int r = 0; r < 4; ++r) {
          v[r] = s0[r];
          v[4 + r] = s1[r];
        }
      } else {
#pragma unroll
        for (int r = 0; r < 4; ++r) {
          int key0 = k0 + 8 * g + 2 * r;
          v[r] = (key0 <= q_glob) ? s0[r] : -1e30f;
          v[4 + r] = (key0 + 1 <= q_glob) ? s1[r] : -1e30f;
        }
      }
      // per-lane max of its 8 keys; defer-max vote needs no cross-lane reduce
      float mloc = fmaxf(fmaxf(fmaxf(v[0], v[1]), fmaxf(v[2], v[3])),
                         fmaxf(fmaxf(v[4], v[5]), fmaxf(v[6], v[7])));
      if (!__all(mloc <= m_run + THR_L2)) {  // slow path: true row-max + rescale
        float mx = fmaxf(mloc, __shfl_xor(mloc, 16));
        mx = fmaxf(mx, __shfl_xor(mx, 32));
        float m_new = fmaxf(m_run, mx);
        float alpha = exp2f(m_run - m_new);
        m_run = m_new;
#pragma unroll
        for (int d = 0; d < 8; ++d)
#pragma unroll
          for (int r = 0; r < 4; ++r) oacc[d][r] *= alpha;  // lane-local
#pragma unroll
        for (int r = 0; r < 4; ++r) oacc_l[r] *= alpha;
      }
      float pex[8];
#pragma unroll
      for (int i = 0; i < 8; ++i) pex[i] = exp2f(v[i] - m_run);
      // PV B-frag: keys 8g..8g+7 = interleave(even pex[0..3], odd pex[4..7])
      bf16x8 pf;
      ((u32*)&pf)[0] = cvtpk(pex[0], pex[4]);
      ((u32*)&pf)[1] = cvtpk(pex[1], pex[5]);
      ((u32*)&pf)[2] = cvtpk(pex[2], pex[6]);
      ((u32*)&pf)[3] = cvtpk(pex[3], pex[7]);
      __builtin_amdgcn_s_setprio(1);
#pragma unroll
      for (int d = 0; d < 8; ++d) {
        bf16x8 vf = *(const bf16x8*)&Vb[(d * 16 + qq) * 32 + ((g ^ vsw) * 8)];
        oacc[d] = MFMA16x16x32(vf, pf, oacc[d], 0, 0, 0);  // O^T: rows=d, cols=q
      }
      oacc_l = MFMA16x16x32(ones, pf, oacc_l, 0, 0, 0);  // l += sum(P) per q-col
      __builtin_amdgcn_s_setprio(0);
    }
    asm volatile("" ::: "memory");
    __builtin_amdgcn_s_barrier();
  }
#undef STAGE
  // epilogue: lane-local 1/l; lane owns q-row (qrow0+qq), d = dtile*16+4g+r
  float linv = 1.f / oacc_l[0];
  const int b = bh >> 4, h = bh & 15;
  size_t rowoff = ((size_t)b * 2048 + qrow0 + qq) * 2048 + h * 128 + 4 * g;
#pragma unroll
  for (int d = 0; d < 8; ++d) {
    u32 lo = cvtpk(oacc[d][0] * linv, oacc[d][1] * linv);
    u32 hi = cvtpk(oacc[d][2] * linv, oacc[d][3] * linv);
    u64 w = (u64)lo | ((u64)hi << 32);
    *(u64*)&O[rowoff + d * 16] = w;
  }
}

// ---------------------------------------------------------------------------
extern "C" void kernel_launch(void* const* d_in, const int* in_sizes, int n_in,
                              void* d_out, int out_size, void* d_ws,
                              size_t ws_size, hipStream_t stream) {
  (void)in_sizes; (void)n_in; (void)out_size;
  const float* x = (const float*)d_in[0];
  const float* fc = (const float*)d_in[1];
  const float* wqa = (const float*)d_in[2];
  const float* wqb = (const float*)d_in[3];
  const float* qnw = (const float*)d_in[4];
  const float* wkva = (const float*)d_in[5];
  const float* kvnw = (const float*)d_in[6];
  const float* wkvb = (const float*)d_in[7];
  const float* wo = (const float*)d_in[8];
  float* out = (float*)d_out;
  char* ws = (char*)d_ws;

  size_t off = 0;
  auto alloc = [&](size_t bytes) {
    size_t o = off;
    off += (bytes + 255) & ~(size_t)255;
    return o;
  };
  const size_t o_xbf = alloc(16777216);   // x bf16; later aliased by attn_out
  const size_t o_wa = alloc(4456448);     // merged [wq_a;wkv_a] bf16 (1088x2048)
  const size_t o_wqb = alloc(3145728);
  const size_t o_wkvb = alloc(4194304);
  const size_t o_wo = alloc(8388608);
  const size_t o_qln = alloc(4194304);    // q_lat normed bf16
  const size_t o_kvln = alloc(4194304);   // kv_lat normed bf16
  const size_t o_kpe = alloc(524288);     // roped k_pe bf16
  const size_t o_big = alloc(67108864);   // f32: aproj -> qfull -> kvb
  const size_t o_qbf = alloc(25165824);   // q packed [bh][s][192] (pre-scaled)
  const size_t o_kbf = alloc(25165824);   // k packed [bh][s][192]
  const size_t o_vt = alloc(16777216);    // v^T [bh][128][2048]
  if (ws_size < off) return;

  u16* xbf = (u16*)(ws + o_xbf);
  u16* wab = (u16*)(ws + o_wa);           // rows 0..511 wq_a, 512..1087 wkv_a
  u16* wqbb = (u16*)(ws + o_wqb);
  u16* wkvbb = (u16*)(ws + o_wkvb);
  u16* wob = (u16*)(ws + o_wo);
  u16* qlatn = (u16*)(ws + o_qln);
  u16* kvlatn = (u16*)(ws + o_kvln);
  u16* kpe = (u16*)(ws + o_kpe);
  float* aproj = (float*)(ws + o_big);    // 4096x1088 f32
  float* qfull = (float*)(ws + o_big);    // 4096x3072 f32 (after aproj dead)
  float* kvb = (float*)(ws + o_big);      // 4096x4096 f32 (after qfull dead)
  u16* qbf = (u16*)(ws + o_qbf);
  u16* kbf = (u16*)(ws + o_kbf);
  u16* vt = (u16*)(ws + o_vt);
  u16* attnbf = (u16*)(ws + o_xbf);       // aliases xbf (dead after aproj)

  // one fused cvt dispatch for x + 5 weights
  cvt_all<<<2048, 256, 0, stream>>>(x, wqa, wkva, wqb, wkvb, wo,
                                    xbf, wab, wab + 1048576, wqbb, wkvbb, wob);

  // merged down-projection: [q_lat | kv_lat | k_pe] = x @ [wq_a;wkv_a]^T
  gemm_bt<64><<<dim3(17, 32), 256, 0, stream>>>(xbf, wab, aproj, 4096, 1088, 2048);
  rmsnorm_bf16<<<4096, 256, 0, stream>>>(aproj, 1088, qnw, qlatn);
  rmsnorm_bf16<<<4096, 256, 0, stream>>>(aproj + 512, 1088, kvnw, kvlatn);
  rope_kpe<<<512, 256, 0, stream>>>(aproj, fc, kpe);

  // q = rmsnorm(q_lat) @ wq_b^T -> rope+scale+pack
  gemm_bt<128><<<dim3(24, 32), 256, 0, stream>>>(qlatn, wqbb, qfull, 4096, 3072, 512);
  rope_pack_q<<<24576, 256, 0, stream>>>(qfull, fc, qbf);

  // kv = rmsnorm(kv_lat) @ wkv_b^T -> pack k, transpose v
  gemm_bt<128><<<dim3(32, 32), 256, 0, stream>>>(kvlatn, wkvbb, kvb, 4096, 4096, 512);
  pack_k<<<24576, 256, 0, stream>>>(kvb, kpe, kbf);
  transpose_v<<<dim3(64, 4, 32), 256, 0, stream>>>(kvb, vt);

  // attention + output projection
  flash_attn<<<1024, 256, 0, stream>>>(qbf, kbf, vt, attnbf);
  gemm_bt<128><<<dim3(16, 32), 256, 0, stream>>>(attnbf, wob, out, 4096, 2048, 2048);
}